// Round 18
// baseline (540.252 us; speedup 1.0000x reference)
//
#include <hip/hip_runtime.h>
#include <hip/hip_fp16.h>
#include <math.h>

#define NN 50000
#define NE 800000
#define NEG 0.2f
#define EPS_BN 1e-5f
#define NROW 8192   // k_gatn grid rows (2048 blocks x 4 waves)
#define NGB  (NROW / 4)   // 2048 k_gatn blocks
#define NB_SC ((NN + 255) / 256)   // 196 scan blocks

typedef _Float16 f16x8 __attribute__((ext_vector_type(8)));
typedef float f32x4 __attribute__((ext_vector_type(4)));

struct __align__(16) Edge { int s; float e0, e1, e2; };

__device__ __forceinline__ float lrelu(float x){ return x > 0.f ? x : NEG * x; }
__device__ __forceinline__ float elu(float x){ return x > 0.f ? x : expm1f(x); }

// ---------------- CSR build ----------------
__global__ __launch_bounds__(256) void k_deg(const int* __restrict__ dst, int* __restrict__ deg){
  int e = blockIdx.x * 256 + threadIdx.x;
  if (e >= NE) return;
  atomicAdd(&deg[dst[e]], 1);
}

// 3-phase scan
__global__ __launch_bounds__(256) void k_scan1(const int* __restrict__ deg, int* __restrict__ bsum){
  __shared__ int sd[4];
  int t = threadIdx.x;
  int i = blockIdx.x * 256 + t;
  int v = (i < NN) ? deg[i] : 0;
  int s = v;
#pragma unroll
  for (int off = 32; off; off >>= 1) s += __shfl_down(s, off, 64);
  if ((t & 63) == 0) sd[t >> 6] = s;
  __syncthreads();
  if (t == 0) bsum[blockIdx.x] = sd[0] + sd[1] + sd[2] + sd[3];
}

__global__ __launch_bounds__(256) void k_scan2(int* __restrict__ bsum, int* __restrict__ rowptr){
  __shared__ int sm[256];
  int t = threadIdx.x;
  int v = (t < NB_SC) ? bsum[t] : 0;
  sm[t] = v;
  __syncthreads();
  for (int off = 1; off < 256; off <<= 1){
    int p = (t >= off) ? sm[t - off] : 0;
    __syncthreads();
    sm[t] += p;
    __syncthreads();
  }
  if (t < NB_SC) bsum[t] = sm[t] - v;
  if (t == 0) rowptr[NN] = NE;
}

__global__ __launch_bounds__(256) void k_scan3(const int* __restrict__ deg, const int* __restrict__ bsum,
                                               int* __restrict__ rowptr){
  __shared__ int sm[256];
  int t = threadIdx.x;
  int i = blockIdx.x * 256 + t;
  int v = (i < NN) ? deg[i] : 0;
  sm[t] = v;
  __syncthreads();
  for (int off = 1; off < 256; off <<= 1){
    int p = (t >= off) ? sm[t - off] : 0;
    __syncthreads();
    sm[t] += p;
    __syncthreads();
  }
  if (i < NN) rowptr[i] = bsum[blockIdx.x] + sm[t] - v;
}

__global__ __launch_bounds__(256) void k_fill(const int* __restrict__ src, const int* __restrict__ dst,
                                              const float* __restrict__ ea, const int* __restrict__ rowptr,
                                              int* __restrict__ cnt, Edge* __restrict__ edges){
  int e = blockIdx.x * 256 + threadIdx.x;
  if (e >= NE) return;
  int d = dst[e];
  int pos = rowptr[d] + atomicAdd(&cnt[d], 1);
  Edge ed;
  ed.s = src[e];
  ed.e0 = ea[e*3+0]; ed.e1 = ea[e*3+1]; ed.e2 = ea[e*3+2];
  edges[pos] = ed;
}

// easum[n] = sum of edge attrs over node n's CSR segment (1 wave/node)
__global__ __launch_bounds__(256) void k_easum(const int* __restrict__ rowptr, const Edge* __restrict__ edges,
                                               float* __restrict__ easum){
  int n = blockIdx.x * 4 + (threadIdx.x >> 6);
  int c = threadIdx.x & 63;
  if (n >= NN) return;
  int start = rowptr[n], end = rowptr[n + 1];
  float s0 = 0.f, s1 = 0.f, s2 = 0.f;
  for (int p = start + c; p < end; p += 64){
    Edge e = edges[p];
    s0 += e.e0; s1 += e.e1; s2 += e.e2;
  }
#pragma unroll
  for (int off = 32; off; off >>= 1){
    s0 += __shfl_down(s0, off, 64);
    s1 += __shfl_down(s1, off, 64);
    s2 += __shfl_down(s2, off, 64);
  }
  if (c == 0){ easum[n*3+0] = s0; easum[n*3+1] = s1; easum[n*3+2] = s2; }
}

// ---------------- input projection ----------------
__global__ __launch_bounds__(256) void k_proj(const float* __restrict__ x, const float* __restrict__ Wp,
                                              const float* __restrict__ bp, float* __restrict__ h0){
  int i = blockIdx.x * 256 + threadIdx.x;
  if (i >= NN * 64) return;
  int n = i >> 6, c = i & 63;
  h0[i] = fmaf(x[n*2+0], Wp[c], fmaf(x[n*2+1], Wp[64+c], bp[c]));
}

// ---------------- BatchNorm stats (64-ch path for layer 1 input) ----------------
template<int F>
__global__ void k_bn_stats(const float* __restrict__ x, float* __restrict__ ps, float* __restrict__ pq){
  int t = threadIdx.x;  // blockDim == F
  float s = 0.f, s2 = 0.f;
  for (int n = blockIdx.x; n < NN; n += 512){
    float v = x[(long)n * F + t];
    s += v; s2 += v * v;
  }
  ps[blockIdx.x * F + t] = s;
  pq[blockIdx.x * F + t] = s2;
}

template<int F>
__global__ void k_bn_fin(const float* __restrict__ ps, const float* __restrict__ pq,
                         float* __restrict__ mu, float* __restrict__ rs){
  int t = threadIdx.x;  // blockDim == F
  float s = 0.f, s2 = 0.f;
  for (int b = 0; b < 512; b++){ s += ps[b * F + t]; s2 += pq[b * F + t]; }
  float m = s * (1.f / NN);
  float var = s2 * (1.f / NN) - m * m;
  mu[t] = m;
  rs[t] = rsqrtf(var + EPS_BN);
}

// ---------------- 256-ch BN finalize from k_gatn's per-WAVE row partials ----------------
__global__ __launch_bounds__(256) void k_bn_fin8192(const float* __restrict__ pbs, const float* __restrict__ pbq,
                                                    float* __restrict__ mu, float* __restrict__ rs){
  __shared__ float sd[2][4];
  int c = blockIdx.x;
  int t = threadIdx.x;
  float s = 0.f, q = 0.f;
  for (int i = t; i < NROW; i += 256){ s += pbs[(long)i * 256 + c]; q += pbq[(long)i * 256 + c]; }
#pragma unroll
  for (int off = 32; off; off >>= 1){ s += __shfl_down(s, off, 64); q += __shfl_down(q, off, 64); }
  if ((t & 63) == 0){ sd[0][t >> 6] = s; sd[1][t >> 6] = q; }
  __syncthreads();
  if (t == 0){
    s = sd[0][0] + sd[0][1] + sd[0][2] + sd[0][3];
    q = sd[1][0] + sd[1][1] + sd[1][2] + sd[1][3];
    float m = s * (1.f / NN);
    float var = q * (1.f / NN) - m * m;
    mu[c] = m;
    rs[c] = rsqrtf(var + EPS_BN);
  }
}

// ---------------- all three weight transposes in one launch ----------------
__global__ __launch_bounds__(256) void k_wt3(const float* __restrict__ W1, const float* __restrict__ W2,
                                             const float* __restrict__ W3, __half* __restrict__ Wt1,
                                             __half* __restrict__ Wt2, __half* __restrict__ Wt3){
  int t = blockIdx.x * 256 + threadIdx.x;
  if (t < 64 * 256){
    int k = t / 256, j = t % 256;
    Wt1[(long)j * 64 + k] = __float2half(W1[t]);
  }
  if (t < 256 * 256){
    int k = t / 256, j = t % 256;
    Wt2[(long)j * 256 + k] = __float2half(W2[t]);
  }
  if (t < 256 * 64){
    int k = t / 64, j = t % 64;
    Wt3[(long)j * 256 + k] = __float2half(W3[t]);
  }
}

// ---------------- g[d][h] = sum_c We[d, h*64+c] * ae[h,c] ----------------
template<int H>
__global__ void k_edge_g(const float* __restrict__ We, const float* __restrict__ ae, float* __restrict__ g){
  int t = threadIdx.x;              // blockDim = H*64
  int h = t >> 6, c = t & 63;
  float a = ae[t];
  for (int d = 0; d < 3; d++){
    float p = We[d * (H*64) + t] * a;
    for (int off = 32; off; off >>= 1) p += __shfl_down(p, off, 64);
    if (c == 0) g[d * H + h] = p;
  }
  (void)h;
}

// ---------------- MFMA GEMM with fused BN+ELU on A and fused attn-coeff epilogue ----------------
template<int K, int J>
__global__ __launch_bounds__(256) void k_gemm_mfma(const float* __restrict__ A, const __half* __restrict__ Wt,
                                                   const float* __restrict__ mu, const float* __restrict__ rs,
                                                   const float* __restrict__ asrc, const float* __restrict__ adst,
                                                   __half* __restrict__ C, float* __restrict__ aS,
                                                   float* __restrict__ aD){
  constexpr int NS = J / 16;
  constexpr int KT = K / 32;
  constexpr int HH = J / 64;
  __shared__ __half Bs[J][40];
  int t = threadIdx.x;
  int w = t >> 6;
  int l = t & 63;
  int row0 = blockIdx.x * 64;
  int lr = l & 15;
  int lg = l >> 4;

  f32x4 acc[NS];
#pragma unroll
  for (int s = 0; s < NS; s++) acc[s] = (f32x4){0.f, 0.f, 0.f, 0.f};

  int arow = row0 + w * 16 + lr;
  bool aval = arow < NN;
  const float* Arow = A + (long)arow * K;

  auto loadA = [&](int kt) -> f16x8 {
    f16x8 r;
#pragma unroll
    for (int k = 0; k < 8; k++) r[k] = (_Float16)0.f;
    if (aval){
      int k0 = kt * 32 + lg * 8;
      float4 q0 = *(const float4*)&Arow[k0];
      float4 q1 = *(const float4*)&Arow[k0 + 4];
      float4 m0 = *(const float4*)&mu[k0];
      float4 m1 = *(const float4*)&mu[k0 + 4];
      float4 r0 = *(const float4*)&rs[k0];
      float4 r1 = *(const float4*)&rs[k0 + 4];
      r[0] = (_Float16)elu((q0.x - m0.x) * r0.x);
      r[1] = (_Float16)elu((q0.y - m0.y) * r0.y);
      r[2] = (_Float16)elu((q0.z - m0.z) * r0.z);
      r[3] = (_Float16)elu((q0.w - m0.w) * r0.w);
      r[4] = (_Float16)elu((q1.x - m1.x) * r1.x);
      r[5] = (_Float16)elu((q1.y - m1.y) * r1.y);
      r[6] = (_Float16)elu((q1.z - m1.z) * r1.z);
      r[7] = (_Float16)elu((q1.w - m1.w) * r1.w);
    }
    return r;
  };

  f16x8 af_cur = loadA(0);

  for (int kt = 0; kt < KT; kt++){
    int kk = kt * 32;
#pragma unroll
    for (int i = 0; i < J / 64; i++){
      int ch = t + 256 * i;
      int c = ch >> 2, q = ch & 3;
      *(uint4*)&Bs[c][q * 8] = *(const uint4*)(Wt + (long)c * K + kk + q * 8);
    }
    __syncthreads();
    f16x8 af_nxt;
#pragma unroll
    for (int k = 0; k < 8; k++) af_nxt[k] = (_Float16)0.f;
    if (kt + 1 < KT) af_nxt = loadA(kt + 1);
#pragma unroll
    for (int s = 0; s < NS; s++){
      f16x8 bf = *(const f16x8*)&Bs[s * 16 + lr][lg * 8];
      acc[s] = __builtin_amdgcn_mfma_f32_16x16x32_f16(af_cur, bf, acc[s], 0, 0, 0);
    }
    __syncthreads();
    af_cur = af_nxt;
  }

  int orow = row0 + w * 16 + lg * 4;
  float sA[HH][4], dA[HH][4];
#pragma unroll
  for (int hd = 0; hd < HH; hd++)
#pragma unroll
    for (int i = 0; i < 4; i++){ sA[hd][i] = 0.f; dA[hd][i] = 0.f; }

#pragma unroll
  for (int s = 0; s < NS; s++){
    int cidx = s * 16 + lr;
    int hd = s >> 2;
    float a1 = asrc[cidx], a2 = adst[cidx];
#pragma unroll
    for (int i = 0; i < 4; i++){
      float v = acc[s][i];
      sA[hd][i] = fmaf(v, a1, sA[hd][i]);
      dA[hd][i] = fmaf(v, a2, dA[hd][i]);
      int r = orow + i;
      if (r < NN) C[(long)r * J + cidx] = __float2half(v);
    }
  }
#pragma unroll
  for (int off = 1; off <= 8; off <<= 1){
#pragma unroll
    for (int hd = 0; hd < HH; hd++)
#pragma unroll
      for (int i = 0; i < 4; i++){
        sA[hd][i] += __shfl_xor(sA[hd][i], off, 64);
        dA[hd][i] += __shfl_xor(dA[hd][i], off, 64);
      }
  }
  if (lr == 0){
#pragma unroll
    for (int i = 0; i < 4; i++){
      int r = orow + i;
      if (r < NN){
#pragma unroll
        for (int hd = 0; hd < HH; hd++){
          aS[r * HH + hd] = sA[hd][i];
          aD[r * HH + hd] = dA[hd][i];
        }
      }
    }
  }
}

// ---------------- H=4 fused GAT: ONE WAVE PER NODE + fused BN stats (no LDS) ----------------
// Agg loop has WAVE-UNIFORM trip count; __shfl executes unconditionally with a
// clamped slot index (CDNA ds_bpermute returns 0 from inactive source lanes).
// STATS: es==0 lanes hold a complete 256-ch partial per wave; written DIRECTLY
// per wave (coalesced 1KB row) — no LDS, no barrier, occupancy preserved.
template<bool STATS>
__global__ __launch_bounds__(256) void k_gatn(const int* __restrict__ rowptr, const Edge* __restrict__ edges,
                                              const int* __restrict__ deg, const float* __restrict__ easum,
                                              const float* __restrict__ aS, const float* __restrict__ aD,
                                              const float* __restrict__ g4, const __half* __restrict__ hh,
                                              const float* __restrict__ bias, float* __restrict__ out,
                                              float* __restrict__ pbs, float* __restrict__ pbq){
  const int W = 256;
  int wid = threadIdx.x >> 6;
  int lane = threadIdx.x & 63;
  int row = blockIdx.x * 4 + wid;      // 0..NROW-1
  int e4 = lane >> 2, hl = lane & 3;   // logit mapping
  int es = lane >> 5, ch8 = lane & 31; // agg mapping
  int c = ch8 * 8;                     // channel base 0..248
  int h2 = ch8 >> 3;                   // head of this channel group
  float g0 = g4[0*4+hl], g1 = g4[1*4+hl], g2 = g4[2*4+hl];
  float4 bb0 = *(const float4*)&bias[c];
  float4 bb1 = *(const float4*)&bias[c+4];
  float sum8[8], sq8[8];
  if (STATS){
#pragma unroll
    for (int k = 0; k < 8; k++){ sum8[k] = 0.f; sq8[k] = 0.f; }
  }

  for (int n = row; n < NN; n += NROW){
    int start = rowptr[n], end = rowptr[n+1];
    float adn = aD[n*4+hl];
    // self-loop (fill_value='mean')
    float dg = (float)deg[n];
    float inv = 1.f / fmaxf(dg, 1.f);
    float ll = aS[n*4+hl] + adn + g0*(easum[n*3+0]*inv) + g1*(easum[n*3+1]*inv) + g2*(easum[n*3+2]*inv);
    ll = lrelu(ll);
    float evl = __expf(ll);
    float evl2 = __shfl(evl, h2, 64);            // lane h2 holds head h2's evl
    f16x8 sv = *(const f16x8*)(hh + (long)n * W + c);
    float acc[8];
#pragma unroll
    for (int k = 0; k < 8; k++) acc[k] = (es == 0) ? evl2 * (float)sv[k] : 0.f;
    float denp = (lane < 4) ? evl : 0.f;

    for (int b0 = start; b0 < end; b0 += 16){
      int len = end - b0; if (len > 16) len = 16;
      float ev = 0.f; unsigned pk = 0;
      if (e4 < len){
        Edge e = edges[b0 + e4];
        float l = lrelu(aS[e.s*4+hl] + adn + g0*e.e0 + g1*e.e1 + g2*e.e2);
        ev = __expf(l);
        pk = ((unsigned)e.s << 16) | (unsigned)__half_as_ushort(__float2half(ev));
      }
      denp += ev;
      int iters = (len + 1) >> 1;                // uniform trip count
      for (int i = 0; i < iters; i++){
        int j = i * 2 + es;                      // may equal len (odd len, es=1)
        bool valid = j < len;
        int jj = valid ? j : 0;
        unsigned pj = __shfl((int)pk, jj * 4 + h2, 64);  // full-wave shuffle: sources active
        float aj = valid ? __half2float(__ushort_as_half((unsigned short)(pj & 0xffffu))) : 0.f;
        int sj = (int)(pj >> 16);
        f16x8 v = *(const f16x8*)(hh + (long)sj * W + c);
#pragma unroll
        for (int k = 0; k < 8; k++) acc[k] = fmaf(aj, (float)v[k], acc[k]);
      }
    }
    // den reduce over e4 (fold bits 2..5), leaves per-head den on lanes by hl
#pragma unroll
    for (int off = 4; off <= 32; off <<= 1) denp += __shfl_xor(denp, off, 64);
    float den2 = __shfl(denp, h2, 64);
    // combine the two edge slots
#pragma unroll
    for (int k = 0; k < 8; k++) acc[k] += __shfl_xor(acc[k], 32, 64);
    if (es == 0){
      float invd = 1.f / (den2 + 1e-16f);
      float o[8];
      o[0] = fmaf(acc[0], invd, bb0.x); o[1] = fmaf(acc[1], invd, bb0.y);
      o[2] = fmaf(acc[2], invd, bb0.z); o[3] = fmaf(acc[3], invd, bb0.w);
      o[4] = fmaf(acc[4], invd, bb1.x); o[5] = fmaf(acc[5], invd, bb1.y);
      o[6] = fmaf(acc[6], invd, bb1.z); o[7] = fmaf(acc[7], invd, bb1.w);
      if (STATS){
#pragma unroll
        for (int k = 0; k < 8; k++){ sum8[k] += o[k]; sq8[k] += o[k]*o[k]; }
      }
      *(float4*)&out[(long)n * W + c]     = make_float4(o[0], o[1], o[2], o[3]);
      *(float4*)&out[(long)n * W + c + 4] = make_float4(o[4], o[5], o[6], o[7]);
    }
  }

  if (STATS && es == 0){
    // per-wave 256-ch partial row: 32 lanes x 32B = coalesced 1KB per array
    *(float4*)&pbs[(long)row * 256 + c]     = make_float4(sum8[0], sum8[1], sum8[2], sum8[3]);
    *(float4*)&pbs[(long)row * 256 + c + 4] = make_float4(sum8[4], sum8[5], sum8[6], sum8[7]);
    *(float4*)&pbq[(long)row * 256 + c]     = make_float4(sq8[0], sq8[1], sq8[2], sq8[3]);
    *(float4*)&pbq[(long)row * 256 + c + 4] = make_float4(sq8[4], sq8[5], sq8[6], sq8[7]);
  }
}

// ---------------- H=1 fused per-wave GAT (layer 3) ----------------
template<int H, bool ELU>
__global__ __launch_bounds__(256) void k_gatw(const int* __restrict__ rowptr, const Edge* __restrict__ edges,
                                              const int* __restrict__ deg, const float* __restrict__ easum,
                                              const float* __restrict__ aS, const float* __restrict__ aD,
                                              const float* __restrict__ g, const __half* __restrict__ hh,
                                              const float* __restrict__ bias, float* __restrict__ out){
  constexpr int W = H * 64;
  int wid = threadIdx.x >> 6;
  int lane = threadIdx.x & 63;
  int n = blockIdx.x * 4 + wid;
  int h = 0;
  if (n >= NN) return;
  int start = rowptr[n], end = rowptr[n + 1];
  float g0 = g[0*H+h], g1 = g[1*H+h], g2 = g[2*H+h];
  float adn = aD[n*H+h];
  int ch8 = lane >> 3;
  int es = lane & 7;

  float dg = (float)deg[n];
  float inv = 1.f / fmaxf(dg, 1.f);
  float ll = aS[n*H+h] + adn + g0*(easum[n*3+0]*inv) + g1*(easum[n*3+1]*inv) + g2*(easum[n*3+2]*inv);
  ll = lrelu(ll);
  float evl = __expf(ll);
  f16x8 sv = *(const f16x8*)(hh + (long)n * W + h * 64 + ch8 * 8);
  float acc[8];
#pragma unroll
  for (int k = 0; k < 8; k++) acc[k] = (es == 0) ? evl * (float)sv[k] : 0.f;
  float denp = (lane == 0) ? evl : 0.f;

  for (int base0 = start; base0 < end; base0 += 64){
    int len = end - base0; if (len > 64) len = 64;
    float ev = 0.f;
    unsigned pk = 0;
    if (lane < len){
      Edge e = edges[base0 + lane];
      float l = lrelu(aS[e.s*H+h] + adn + g0*e.e0 + g1*e.e1 + g2*e.e2);
      ev = __expf(l);
      pk = ((unsigned)e.s << 16) | (unsigned)__half_as_ushort(__float2half(ev));
    }
    denp += ev;
    for (int j = es; j < len; j += 8){
      unsigned pj = __shfl((int)pk, j, 64);
      float aj = __half2float(__ushort_as_half((unsigned short)(pj & 0xffffu)));
      int sj = (int)(pj >> 16);
      f16x8 v = *(const f16x8*)(hh + (long)sj * W + h * 64 + ch8 * 8);
#pragma unroll
      for (int k = 0; k < 8; k++) acc[k] = fmaf(aj, (float)v[k], acc[k]);
    }
  }

#pragma unroll
  for (int off = 32; off; off >>= 1) denp += __shfl_xor(denp, off, 64);
#pragma unroll
  for (int k = 0; k < 8; k++){
    acc[k] += __shfl_xor(acc[k], 1, 64);
    acc[k] += __shfl_xor(acc[k], 2, 64);
    acc[k] += __shfl_xor(acc[k], 4, 64);
  }
  if (es == 0){
    float invden = 1.f / (denp + 1e-16f);
    int cb = h * 64 + ch8 * 8;
    float4 b0 = *(const float4*)&bias[cb];
    float4 b1 = *(const float4*)&bias[cb + 4];
    float bb[8] = {b0.x, b0.y, b0.z, b0.w, b1.x, b1.y, b1.z, b1.w};
#pragma unroll
    for (int k = 0; k < 8; k++){
      acc[k] = acc[k] * invden + bb[k];
      if (ELU) acc[k] = acc[k] > 0.f ? acc[k] : expm1f(acc[k]);
    }
    float4 o0 = make_float4(acc[0], acc[1], acc[2], acc[3]);
    float4 o1 = make_float4(acc[4], acc[5], acc[6], acc[7]);
    *(float4*)&out[(long)n * W + cb] = o0;
    *(float4*)&out[(long)n * W + cb + 4] = o1;
  }
}

// ---------------- final linear 64->4 + softmax ----------------
__global__ __launch_bounds__(64) void k_final(const float* __restrict__ h3, const float* __restrict__ Wc,
                                              const float* __restrict__ bc, float* __restrict__ out){
  int n = blockIdx.x;
  int c = threadIdx.x;  // 64
  float v = h3[(long)n * 64 + c];
  float r0 = v * Wc[c*4+0], r1 = v * Wc[c*4+1], r2 = v * Wc[c*4+2], r3 = v * Wc[c*4+3];
  for (int off = 32; off; off >>= 1){
    r0 += __shfl_down(r0, off, 64);
    r1 += __shfl_down(r1, off, 64);
    r2 += __shfl_down(r2, off, 64);
    r3 += __shfl_down(r3, off, 64);
  }
  if (c == 0){
    r0 += bc[0]; r1 += bc[1]; r2 += bc[2]; r3 += bc[3];
    float mm = fmaxf(fmaxf(r0, r1), fmaxf(r2, r3));
    float e0 = __expf(r0 - mm), e1 = __expf(r1 - mm), e2 = __expf(r2 - mm), e3 = __expf(r3 - mm);
    float is = 1.f / (e0 + e1 + e2 + e3);
    out[n*4+0] = e0 * is; out[n*4+1] = e1 * is; out[n*4+2] = e2 * is; out[n*4+3] = e3 * is;
  }
}

extern "C" void kernel_launch(void* const* d_in, const int* in_sizes, int n_in,
                              void* d_out, int out_size, void* d_ws, size_t ws_size,
                              hipStream_t stream){
  const float* x   = (const float*)d_in[0];
  const int*   ei  = (const int*)d_in[1];
  const float* ea  = (const float*)d_in[2];
  const float* Wp  = (const float*)d_in[3];
  const float* bp  = (const float*)d_in[4];
  const float* W1  = (const float*)d_in[5];
  const float* as1 = (const float*)d_in[6];
  const float* ad1 = (const float*)d_in[7];
  const float* We1 = (const float*)d_in[8];
  const float* ae1 = (const float*)d_in[9];
  const float* b1  = (const float*)d_in[10];
  const float* W2  = (const float*)d_in[11];
  const float* as2 = (const float*)d_in[12];
  const float* ad2 = (const float*)d_in[13];
  const float* We2 = (const float*)d_in[14];
  const float* ae2 = (const float*)d_in[15];
  const float* b2  = (const float*)d_in[16];
  const float* W3  = (const float*)d_in[17];
  const float* as3 = (const float*)d_in[18];
  const float* ad3 = (const float*)d_in[19];
  const float* We3 = (const float*)d_in[20];
  const float* ae3 = (const float*)d_in[21];
  const float* b3  = (const float*)d_in[22];
  const float* Wc  = (const float*)d_in[23];
  const float* bc  = (const float*)d_in[24];
  const int* srcI = ei;
  const int* dstI = ei + NE;

  char* base = (char*)d_ws;
  size_t off = 0;
  auto alloc = [&](size_t bytes) -> void* {
    void* p = base + off;
    off += (bytes + 255) & ~(size_t)255;
    return p;
  };
  float*  bufA  = (float*)alloc((size_t)NN * 256 * 4);
  __half* hB    = (__half*)alloc((size_t)NN * 256 * 2);
  __half* Wt1   = (__half*)alloc((size_t)64 * 256 * 2);
  __half* Wt2   = (__half*)alloc((size_t)256 * 256 * 2);
  __half* Wt3   = (__half*)alloc((size_t)256 * 64 * 2);
  int*   deg   = (int*)  alloc((size_t)NN * 4);
  int*   cnt   = (int*)  alloc((size_t)NN * 4);
  int*   rowptr= (int*)  alloc((size_t)(NN + 1) * 4);
  int*   bsum  = (int*)  alloc((size_t)NB_SC * 4);
  Edge*  edges = (Edge*) alloc((size_t)NE * sizeof(Edge));
  float* easum = (float*)alloc((size_t)NN * 3 * 4);
  float* aS    = (float*)alloc((size_t)NN * 4 * 4);
  float* aD    = (float*)alloc((size_t)NN * 4 * 4);
  float* g     = (float*)alloc(256);
  float* pbs   = (float*)alloc((size_t)NROW * 256 * 4);   // 8 MB per-wave partials
  float* pbq   = (float*)alloc((size_t)NROW * 256 * 4);
  float* bmu   = (float*)alloc(256 * 4);
  float* brs   = (float*)alloc(256 * 4);
  (void)ws_size; (void)in_sizes; (void)n_in; (void)out_size;

  // CSR build + weight conversion
  hipMemsetAsync(deg, 0, (size_t)NN * 4, stream);
  hipMemsetAsync(cnt, 0, (size_t)NN * 4, stream);
  k_deg<<<(NE + 255) / 256, 256, 0, stream>>>(dstI, deg);
  k_scan1<<<NB_SC, 256, 0, stream>>>(deg, bsum);
  k_scan2<<<1, 256, 0, stream>>>(bsum, rowptr);
  k_scan3<<<NB_SC, 256, 0, stream>>>(deg, bsum, rowptr);
  k_fill<<<(NE + 255) / 256, 256, 0, stream>>>(srcI, dstI, ea, rowptr, cnt, edges);
  k_easum<<<(NN + 3) / 4, 256, 0, stream>>>(rowptr, edges, easum);
  k_wt3<<<(256 * 256 + 255) / 256, 256, 0, stream>>>(W1, W2, W3, Wt1, Wt2, Wt3);

  // input projection + BN stats (64-ch path)
  k_proj<<<(NN * 64 + 255) / 256, 256, 0, stream>>>(x, Wp, bp, bufA);
  k_bn_stats<64><<<512, 64, 0, stream>>>(bufA, pbs, pbq);
  k_bn_fin<64><<<1, 64, 0, stream>>>(pbs, pbq, bmu, brs);

  // ---- GAT layer 1 (64 -> 4x64); BN stats fused into k_gatn ----
  k_edge_g<4><<<1, 256, 0, stream>>>(We1, ae1, g);
  k_gemm_mfma<64, 256><<<(NN + 63) / 64, 256, 0, stream>>>(bufA, Wt1, bmu, brs, as1, ad1, hB, aS, aD);
  k_gatn<true><<<NGB, 256, 0, stream>>>(rowptr, edges, deg, easum, aS, aD, g, hB, b1, bufA, pbs, pbq);
  k_bn_fin8192<<<256, 256, 0, stream>>>(pbs, pbq, bmu, brs);

  // ---- GAT layer 2 (256 -> 4x64) ----
  k_edge_g<4><<<1, 256, 0, stream>>>(We2, ae2, g);
  k_gemm_mfma<256, 256><<<(NN + 63) / 64, 256, 0, stream>>>(bufA, Wt2, bmu, brs, as2, ad2, hB, aS, aD);
  k_gatn<true><<<NGB, 256, 0, stream>>>(rowptr, edges, deg, easum, aS, aD, g, hB, b2, bufA, pbs, pbq);
  k_bn_fin8192<<<256, 256, 0, stream>>>(pbs, pbq, bmu, brs);

  // ---- GAT layer 3 (256 -> 1x64), ELU fused ----
  k_edge_g<1><<<1, 64, 0, stream>>>(We3, ae3, g);
  k_gemm_mfma<256, 64><<<(NN + 63) / 64, 256, 0, stream>>>(bufA, Wt3, bmu, brs, as3, ad3, hB, aS, aD);
  k_gatw<1, true><<<(NN + 3) / 4, 256, 0, stream>>>(rowptr, edges, deg, easum, aS, aD, g, hB, b3, bufA);

  // ---- classifier + softmax ----
  k_final<<<NN, 64, 0, stream>>>(bufA, Wc, bc, (float*)d_out);
}

// Round 19
// 485.106 us; speedup vs baseline: 1.1137x; 1.1137x over previous
//
#include <hip/hip_runtime.h>
#include <hip/hip_fp16.h>
#include <math.h>

#define NN 50000
#define NE 800000
#define NEG 0.2f
#define EPS_BN 1e-5f
#define NROW 16384  // k_gatn grid rows (4096 blocks x 4 waves)
#define NGB  (NROW / 4)   // 4096 k_gatn blocks
#define NB_SC ((NN + 255) / 256)   // 196 scan blocks

typedef _Float16 f16x8 __attribute__((ext_vector_type(8)));
typedef float f32x4 __attribute__((ext_vector_type(4)));

struct __align__(16) Edge { int s; float e0, e1, e2; };

__device__ __forceinline__ float lrelu(float x){ return x > 0.f ? x : NEG * x; }
__device__ __forceinline__ float elu(float x){ return x > 0.f ? x : expm1f(x); }

// ---------------- CSR build ----------------
__global__ __launch_bounds__(256) void k_deg(const int* __restrict__ dst, int* __restrict__ deg){
  int e = blockIdx.x * 256 + threadIdx.x;
  if (e >= NE) return;
  atomicAdd(&deg[dst[e]], 1);
}

// 3-phase scan
__global__ __launch_bounds__(256) void k_scan1(const int* __restrict__ deg, int* __restrict__ bsum){
  __shared__ int sd[4];
  int t = threadIdx.x;
  int i = blockIdx.x * 256 + t;
  int v = (i < NN) ? deg[i] : 0;
  int s = v;
#pragma unroll
  for (int off = 32; off; off >>= 1) s += __shfl_down(s, off, 64);
  if ((t & 63) == 0) sd[t >> 6] = s;
  __syncthreads();
  if (t == 0) bsum[blockIdx.x] = sd[0] + sd[1] + sd[2] + sd[3];
}

__global__ __launch_bounds__(256) void k_scan2(int* __restrict__ bsum, int* __restrict__ rowptr){
  __shared__ int sm[256];
  int t = threadIdx.x;
  int v = (t < NB_SC) ? bsum[t] : 0;
  sm[t] = v;
  __syncthreads();
  for (int off = 1; off < 256; off <<= 1){
    int p = (t >= off) ? sm[t - off] : 0;
    __syncthreads();
    sm[t] += p;
    __syncthreads();
  }
  if (t < NB_SC) bsum[t] = sm[t] - v;
  if (t == 0) rowptr[NN] = NE;
}

__global__ __launch_bounds__(256) void k_scan3(const int* __restrict__ deg, const int* __restrict__ bsum,
                                               int* __restrict__ rowptr){
  __shared__ int sm[256];
  int t = threadIdx.x;
  int i = blockIdx.x * 256 + t;
  int v = (i < NN) ? deg[i] : 0;
  sm[t] = v;
  __syncthreads();
  for (int off = 1; off < 256; off <<= 1){
    int p = (t >= off) ? sm[t - off] : 0;
    __syncthreads();
    sm[t] += p;
    __syncthreads();
  }
  if (i < NN) rowptr[i] = bsum[blockIdx.x] + sm[t] - v;
}

__global__ __launch_bounds__(256) void k_fill(const int* __restrict__ src, const int* __restrict__ dst,
                                              const float* __restrict__ ea, const int* __restrict__ rowptr,
                                              int* __restrict__ cnt, Edge* __restrict__ edges){
  int e = blockIdx.x * 256 + threadIdx.x;
  if (e >= NE) return;
  int d = dst[e];
  int pos = rowptr[d] + atomicAdd(&cnt[d], 1);
  Edge ed;
  ed.s = src[e];
  ed.e0 = ea[e*3+0]; ed.e1 = ea[e*3+1]; ed.e2 = ea[e*3+2];
  edges[pos] = ed;
}

// easum[n] = sum of edge attrs over node n's CSR segment (1 wave/node)
__global__ __launch_bounds__(256) void k_easum(const int* __restrict__ rowptr, const Edge* __restrict__ edges,
                                               float* __restrict__ easum){
  int n = blockIdx.x * 4 + (threadIdx.x >> 6);
  int c = threadIdx.x & 63;
  if (n >= NN) return;
  int start = rowptr[n], end = rowptr[n + 1];
  float s0 = 0.f, s1 = 0.f, s2 = 0.f;
  for (int p = start + c; p < end; p += 64){
    Edge e = edges[p];
    s0 += e.e0; s1 += e.e1; s2 += e.e2;
  }
#pragma unroll
  for (int off = 32; off; off >>= 1){
    s0 += __shfl_down(s0, off, 64);
    s1 += __shfl_down(s1, off, 64);
    s2 += __shfl_down(s2, off, 64);
  }
  if (c == 0){ easum[n*3+0] = s0; easum[n*3+1] = s1; easum[n*3+2] = s2; }
}

// ---------------- input projection ----------------
__global__ __launch_bounds__(256) void k_proj(const float* __restrict__ x, const float* __restrict__ Wp,
                                              const float* __restrict__ bp, float* __restrict__ h0){
  int i = blockIdx.x * 256 + threadIdx.x;
  if (i >= NN * 64) return;
  int n = i >> 6, c = i & 63;
  h0[i] = fmaf(x[n*2+0], Wp[c], fmaf(x[n*2+1], Wp[64+c], bp[c]));
}

// ---------------- BatchNorm stats (64-ch path for layer 1 input) ----------------
template<int F>
__global__ void k_bn_stats(const float* __restrict__ x, float* __restrict__ ps, float* __restrict__ pq){
  int t = threadIdx.x;  // blockDim == F
  float s = 0.f, s2 = 0.f;
  for (int n = blockIdx.x; n < NN; n += 512){
    float v = x[(long)n * F + t];
    s += v; s2 += v * v;
  }
  ps[blockIdx.x * F + t] = s;
  pq[blockIdx.x * F + t] = s2;
}

template<int F>
__global__ void k_bn_fin(const float* __restrict__ ps, const float* __restrict__ pq,
                         float* __restrict__ mu, float* __restrict__ rs){
  int t = threadIdx.x;  // blockDim == F
  float s = 0.f, s2 = 0.f;
  for (int b = 0; b < 512; b++){ s += ps[b * F + t]; s2 += pq[b * F + t]; }
  float m = s * (1.f / NN);
  float var = s2 * (1.f / NN) - m * m;
  mu[t] = m;
  rs[t] = rsqrtf(var + EPS_BN);
}

// ---------------- 256-ch BN finalize from k_gatn's BLOCK-MAJOR partials ----------------
__global__ __launch_bounds__(256) void k_bn_finP(const float* __restrict__ pbs, const float* __restrict__ pbq,
                                                 float* __restrict__ mu, float* __restrict__ rs){
  __shared__ float sd[2][4];
  int c = blockIdx.x;
  int t = threadIdx.x;
  float s = 0.f, q = 0.f;
  for (int i = t; i < NGB; i += 256){ s += pbs[(long)i * 256 + c]; q += pbq[(long)i * 256 + c]; }
#pragma unroll
  for (int off = 32; off; off >>= 1){ s += __shfl_down(s, off, 64); q += __shfl_down(q, off, 64); }
  if ((t & 63) == 0){ sd[0][t >> 6] = s; sd[1][t >> 6] = q; }
  __syncthreads();
  if (t == 0){
    s = sd[0][0] + sd[0][1] + sd[0][2] + sd[0][3];
    q = sd[1][0] + sd[1][1] + sd[1][2] + sd[1][3];
    float m = s * (1.f / NN);
    float var = q * (1.f / NN) - m * m;
    mu[c] = m;
    rs[c] = rsqrtf(var + EPS_BN);
  }
}

// ---------------- all three weight transposes in one launch ----------------
__global__ __launch_bounds__(256) void k_wt3(const float* __restrict__ W1, const float* __restrict__ W2,
                                             const float* __restrict__ W3, __half* __restrict__ Wt1,
                                             __half* __restrict__ Wt2, __half* __restrict__ Wt3){
  int t = blockIdx.x * 256 + threadIdx.x;
  if (t < 64 * 256){
    int k = t / 256, j = t % 256;
    Wt1[(long)j * 64 + k] = __float2half(W1[t]);
  }
  if (t < 256 * 256){
    int k = t / 256, j = t % 256;
    Wt2[(long)j * 256 + k] = __float2half(W2[t]);
  }
  if (t < 256 * 64){
    int k = t / 64, j = t % 64;
    Wt3[(long)j * 256 + k] = __float2half(W3[t]);
  }
}

// ---------------- g[d][h] = sum_c We[d, h*64+c] * ae[h,c] ----------------
template<int H>
__global__ void k_edge_g(const float* __restrict__ We, const float* __restrict__ ae, float* __restrict__ g){
  int t = threadIdx.x;              // blockDim = H*64
  int h = t >> 6, c = t & 63;
  float a = ae[t];
  for (int d = 0; d < 3; d++){
    float p = We[d * (H*64) + t] * a;
    for (int off = 32; off; off >>= 1) p += __shfl_down(p, off, 64);
    if (c == 0) g[d * H + h] = p;
  }
  (void)h;
}

// ---------------- MFMA GEMM with fused BN+ELU on A and fused attn-coeff epilogue ----------------
template<int K, int J>
__global__ __launch_bounds__(256) void k_gemm_mfma(const float* __restrict__ A, const __half* __restrict__ Wt,
                                                   const float* __restrict__ mu, const float* __restrict__ rs,
                                                   const float* __restrict__ asrc, const float* __restrict__ adst,
                                                   __half* __restrict__ C, float* __restrict__ aS,
                                                   float* __restrict__ aD){
  constexpr int NS = J / 16;
  constexpr int KT = K / 32;
  constexpr int HH = J / 64;
  __shared__ __half Bs[J][40];
  int t = threadIdx.x;
  int w = t >> 6;
  int l = t & 63;
  int row0 = blockIdx.x * 64;
  int lr = l & 15;
  int lg = l >> 4;

  f32x4 acc[NS];
#pragma unroll
  for (int s = 0; s < NS; s++) acc[s] = (f32x4){0.f, 0.f, 0.f, 0.f};

  int arow = row0 + w * 16 + lr;
  bool aval = arow < NN;
  const float* Arow = A + (long)arow * K;

  auto loadA = [&](int kt) -> f16x8 {
    f16x8 r;
#pragma unroll
    for (int k = 0; k < 8; k++) r[k] = (_Float16)0.f;
    if (aval){
      int k0 = kt * 32 + lg * 8;
      float4 q0 = *(const float4*)&Arow[k0];
      float4 q1 = *(const float4*)&Arow[k0 + 4];
      float4 m0 = *(const float4*)&mu[k0];
      float4 m1 = *(const float4*)&mu[k0 + 4];
      float4 r0 = *(const float4*)&rs[k0];
      float4 r1 = *(const float4*)&rs[k0 + 4];
      r[0] = (_Float16)elu((q0.x - m0.x) * r0.x);
      r[1] = (_Float16)elu((q0.y - m0.y) * r0.y);
      r[2] = (_Float16)elu((q0.z - m0.z) * r0.z);
      r[3] = (_Float16)elu((q0.w - m0.w) * r0.w);
      r[4] = (_Float16)elu((q1.x - m1.x) * r1.x);
      r[5] = (_Float16)elu((q1.y - m1.y) * r1.y);
      r[6] = (_Float16)elu((q1.z - m1.z) * r1.z);
      r[7] = (_Float16)elu((q1.w - m1.w) * r1.w);
    }
    return r;
  };

  f16x8 af_cur = loadA(0);

  for (int kt = 0; kt < KT; kt++){
    int kk = kt * 32;
#pragma unroll
    for (int i = 0; i < J / 64; i++){
      int ch = t + 256 * i;
      int c = ch >> 2, q = ch & 3;
      *(uint4*)&Bs[c][q * 8] = *(const uint4*)(Wt + (long)c * K + kk + q * 8);
    }
    __syncthreads();
    f16x8 af_nxt;
#pragma unroll
    for (int k = 0; k < 8; k++) af_nxt[k] = (_Float16)0.f;
    if (kt + 1 < KT) af_nxt = loadA(kt + 1);
#pragma unroll
    for (int s = 0; s < NS; s++){
      f16x8 bf = *(const f16x8*)&Bs[s * 16 + lr][lg * 8];
      acc[s] = __builtin_amdgcn_mfma_f32_16x16x32_f16(af_cur, bf, acc[s], 0, 0, 0);
    }
    __syncthreads();
    af_cur = af_nxt;
  }

  int orow = row0 + w * 16 + lg * 4;
  float sA[HH][4], dA[HH][4];
#pragma unroll
  for (int hd = 0; hd < HH; hd++)
#pragma unroll
    for (int i = 0; i < 4; i++){ sA[hd][i] = 0.f; dA[hd][i] = 0.f; }

#pragma unroll
  for (int s = 0; s < NS; s++){
    int cidx = s * 16 + lr;
    int hd = s >> 2;
    float a1 = asrc[cidx], a2 = adst[cidx];
#pragma unroll
    for (int i = 0; i < 4; i++){
      float v = acc[s][i];
      sA[hd][i] = fmaf(v, a1, sA[hd][i]);
      dA[hd][i] = fmaf(v, a2, dA[hd][i]);
      int r = orow + i;
      if (r < NN) C[(long)r * J + cidx] = __float2half(v);
    }
  }
#pragma unroll
  for (int off = 1; off <= 8; off <<= 1){
#pragma unroll
    for (int hd = 0; hd < HH; hd++)
#pragma unroll
      for (int i = 0; i < 4; i++){
        sA[hd][i] += __shfl_xor(sA[hd][i], off, 64);
        dA[hd][i] += __shfl_xor(dA[hd][i], off, 64);
      }
  }
  if (lr == 0){
#pragma unroll
    for (int i = 0; i < 4; i++){
      int r = orow + i;
      if (r < NN){
#pragma unroll
        for (int hd = 0; hd < HH; hd++){
          aS[r * HH + hd] = sA[hd][i];
          aD[r * HH + hd] = dA[hd][i];
        }
      }
    }
  }
}

// ---------------- H=4 fused GAT: ONE WAVE PER NODE + fused BN stats ----------------
// Agg loop has WAVE-UNIFORM trip count; __shfl executes unconditionally with a
// clamped slot index (CDNA ds_bpermute returns 0 from inactive source lanes).
// Register-diet epilogue: bias loaded per node (not hoisted), acc normalized in
// place (no o[] temp) — keeps the loop-carried live set small. Stats partials
// combined across waves in LDS, written block-major (coalesced 1KB/block).
template<bool STATS>
__global__ __launch_bounds__(256) void k_gatn(const int* __restrict__ rowptr, const Edge* __restrict__ edges,
                                              const int* __restrict__ deg, const float* __restrict__ easum,
                                              const float* __restrict__ aS, const float* __restrict__ aD,
                                              const float* __restrict__ g4, const __half* __restrict__ hh,
                                              const float* __restrict__ bias, float* __restrict__ out,
                                              float* __restrict__ pbs, float* __restrict__ pbq){
  const int W = 256;
  int wid = threadIdx.x >> 6;
  int lane = threadIdx.x & 63;
  int row = blockIdx.x * 4 + wid;      // 0..NROW-1
  int e4 = lane >> 2, hl = lane & 3;   // logit mapping
  int es = lane >> 5, ch8 = lane & 31; // agg mapping
  int c = ch8 * 8;                     // channel base 0..248
  int h2 = ch8 >> 3;                   // head of this channel group
  float g0 = g4[0*4+hl], g1 = g4[1*4+hl], g2 = g4[2*4+hl];
  float sum8[8], sq8[8];
  if (STATS){
#pragma unroll
    for (int k = 0; k < 8; k++){ sum8[k] = 0.f; sq8[k] = 0.f; }
  }

  for (int n = row; n < NN; n += NROW){
    int start = rowptr[n], end = rowptr[n+1];
    float adn = aD[n*4+hl];
    // self-loop (fill_value='mean')
    float dg = (float)deg[n];
    float inv = 1.f / fmaxf(dg, 1.f);
    float ll = aS[n*4+hl] + adn + g0*(easum[n*3+0]*inv) + g1*(easum[n*3+1]*inv) + g2*(easum[n*3+2]*inv);
    ll = lrelu(ll);
    float evl = __expf(ll);
    float evl2 = __shfl(evl, h2, 64);            // lane h2 holds head h2's evl
    f16x8 sv = *(const f16x8*)(hh + (long)n * W + c);
    float acc[8];
#pragma unroll
    for (int k = 0; k < 8; k++) acc[k] = (es == 0) ? evl2 * (float)sv[k] : 0.f;
    float denp = (lane < 4) ? evl : 0.f;

    for (int b0 = start; b0 < end; b0 += 16){
      int len = end - b0; if (len > 16) len = 16;
      float ev = 0.f; unsigned pk = 0;
      if (e4 < len){
        Edge e = edges[b0 + e4];
        float l = lrelu(aS[e.s*4+hl] + adn + g0*e.e0 + g1*e.e1 + g2*e.e2);
        ev = __expf(l);
        pk = ((unsigned)e.s << 16) | (unsigned)__half_as_ushort(__float2half(ev));
      }
      denp += ev;
      int iters = (len + 1) >> 1;                // uniform trip count
      for (int i = 0; i < iters; i++){
        int j = i * 2 + es;                      // may equal len (odd len, es=1)
        bool valid = j < len;
        int jj = valid ? j : 0;
        unsigned pj = __shfl((int)pk, jj * 4 + h2, 64);  // full-wave shuffle: sources active
        float aj = valid ? __half2float(__ushort_as_half((unsigned short)(pj & 0xffffu))) : 0.f;
        int sj = (int)(pj >> 16);
        f16x8 v = *(const f16x8*)(hh + (long)sj * W + c);
#pragma unroll
        for (int k = 0; k < 8; k++) acc[k] = fmaf(aj, (float)v[k], acc[k]);
      }
    }
    // den reduce over e4 (fold bits 2..5), leaves per-head den on lanes by hl
#pragma unroll
    for (int off = 4; off <= 32; off <<= 1) denp += __shfl_xor(denp, off, 64);
    float den2 = __shfl(denp, h2, 64);
    // combine the two edge slots
#pragma unroll
    for (int k = 0; k < 8; k++) acc[k] += __shfl_xor(acc[k], 32, 64);
    if (es == 0){
      float invd = 1.f / (den2 + 1e-16f);
      float4 b0v = *(const float4*)&bias[c];
      float4 b1v = *(const float4*)&bias[c+4];
      acc[0] = fmaf(acc[0], invd, b0v.x); acc[1] = fmaf(acc[1], invd, b0v.y);
      acc[2] = fmaf(acc[2], invd, b0v.z); acc[3] = fmaf(acc[3], invd, b0v.w);
      acc[4] = fmaf(acc[4], invd, b1v.x); acc[5] = fmaf(acc[5], invd, b1v.y);
      acc[6] = fmaf(acc[6], invd, b1v.z); acc[7] = fmaf(acc[7], invd, b1v.w);
      if (STATS){
#pragma unroll
        for (int k = 0; k < 8; k++){ sum8[k] += acc[k]; sq8[k] += acc[k]*acc[k]; }
      }
      *(float4*)&out[(long)n * W + c]     = make_float4(acc[0], acc[1], acc[2], acc[3]);
      *(float4*)&out[(long)n * W + c + 4] = make_float4(acc[4], acc[5], acc[6], acc[7]);
    }
  }

  if (STATS){
    __shared__ float ls[4][256];
    __shared__ float lq[4][256];
    if (es == 0){
#pragma unroll
      for (int k = 0; k < 8; k++){ ls[wid][c + k] = sum8[k]; lq[wid][c + k] = sq8[k]; }
    }
    __syncthreads();
    int ch = threadIdx.x;   // 256 threads = 256 channels
    float s = ls[0][ch] + ls[1][ch] + ls[2][ch] + ls[3][ch];
    float q = lq[0][ch] + lq[1][ch] + lq[2][ch] + lq[3][ch];
    pbs[(long)blockIdx.x * 256 + ch] = s;   // block-major: coalesced 1KB per block
    pbq[(long)blockIdx.x * 256 + ch] = q;
  }
}

// ---------------- H=1 fused per-wave GAT (layer 3) ----------------
template<int H, bool ELU>
__global__ __launch_bounds__(256) void k_gatw(const int* __restrict__ rowptr, const Edge* __restrict__ edges,
                                              const int* __restrict__ deg, const float* __restrict__ easum,
                                              const float* __restrict__ aS, const float* __restrict__ aD,
                                              const float* __restrict__ g, const __half* __restrict__ hh,
                                              const float* __restrict__ bias, float* __restrict__ out){
  constexpr int W = H * 64;
  int wid = threadIdx.x >> 6;
  int lane = threadIdx.x & 63;
  int n = blockIdx.x * 4 + wid;
  int h = 0;
  if (n >= NN) return;
  int start = rowptr[n], end = rowptr[n + 1];
  float g0 = g[0*H+h], g1 = g[1*H+h], g2 = g[2*H+h];
  float adn = aD[n*H+h];
  int ch8 = lane >> 3;
  int es = lane & 7;

  float dg = (float)deg[n];
  float inv = 1.f / fmaxf(dg, 1.f);
  float ll = aS[n*H+h] + adn + g0*(easum[n*3+0]*inv) + g1*(easum[n*3+1]*inv) + g2*(easum[n*3+2]*inv);
  ll = lrelu(ll);
  float evl = __expf(ll);
  f16x8 sv = *(const f16x8*)(hh + (long)n * W + h * 64 + ch8 * 8);
  float acc[8];
#pragma unroll
  for (int k = 0; k < 8; k++) acc[k] = (es == 0) ? evl * (float)sv[k] : 0.f;
  float denp = (lane == 0) ? evl : 0.f;

  for (int base0 = start; base0 < end; base0 += 64){
    int len = end - base0; if (len > 64) len = 64;
    float ev = 0.f;
    unsigned pk = 0;
    if (lane < len){
      Edge e = edges[base0 + lane];
      float l = lrelu(aS[e.s*H+h] + adn + g0*e.e0 + g1*e.e1 + g2*e.e2);
      ev = __expf(l);
      pk = ((unsigned)e.s << 16) | (unsigned)__half_as_ushort(__float2half(ev));
    }
    denp += ev;
    for (int j = es; j < len; j += 8){
      unsigned pj = __shfl((int)pk, j, 64);
      float aj = __half2float(__ushort_as_half((unsigned short)(pj & 0xffffu)));
      int sj = (int)(pj >> 16);
      f16x8 v = *(const f16x8*)(hh + (long)sj * W + h * 64 + ch8 * 8);
#pragma unroll
      for (int k = 0; k < 8; k++) acc[k] = fmaf(aj, (float)v[k], acc[k]);
    }
  }

#pragma unroll
  for (int off = 32; off; off >>= 1) denp += __shfl_xor(denp, off, 64);
#pragma unroll
  for (int k = 0; k < 8; k++){
    acc[k] += __shfl_xor(acc[k], 1, 64);
    acc[k] += __shfl_xor(acc[k], 2, 64);
    acc[k] += __shfl_xor(acc[k], 4, 64);
  }
  if (es == 0){
    float invden = 1.f / (denp + 1e-16f);
    int cb = h * 64 + ch8 * 8;
    float4 b0 = *(const float4*)&bias[cb];
    float4 b1 = *(const float4*)&bias[cb + 4];
    float bb[8] = {b0.x, b0.y, b0.z, b0.w, b1.x, b1.y, b1.z, b1.w};
#pragma unroll
    for (int k = 0; k < 8; k++){
      acc[k] = acc[k] * invden + bb[k];
      if (ELU) acc[k] = acc[k] > 0.f ? acc[k] : expm1f(acc[k]);
    }
    float4 o0 = make_float4(acc[0], acc[1], acc[2], acc[3]);
    float4 o1 = make_float4(acc[4], acc[5], acc[6], acc[7]);
    *(float4*)&out[(long)n * W + cb] = o0;
    *(float4*)&out[(long)n * W + cb + 4] = o1;
  }
}

// ---------------- final linear 64->4 + softmax ----------------
__global__ __launch_bounds__(64) void k_final(const float* __restrict__ h3, const float* __restrict__ Wc,
                                              const float* __restrict__ bc, float* __restrict__ out){
  int n = blockIdx.x;
  int c = threadIdx.x;  // 64
  float v = h3[(long)n * 64 + c];
  float r0 = v * Wc[c*4+0], r1 = v * Wc[c*4+1], r2 = v * Wc[c*4+2], r3 = v * Wc[c*4+3];
  for (int off = 32; off; off >>= 1){
    r0 += __shfl_down(r0, off, 64);
    r1 += __shfl_down(r1, off, 64);
    r2 += __shfl_down(r2, off, 64);
    r3 += __shfl_down(r3, off, 64);
  }
  if (c == 0){
    r0 += bc[0]; r1 += bc[1]; r2 += bc[2]; r3 += bc[3];
    float mm = fmaxf(fmaxf(r0, r1), fmaxf(r2, r3));
    float e0 = __expf(r0 - mm), e1 = __expf(r1 - mm), e2 = __expf(r2 - mm), e3 = __expf(r3 - mm);
    float is = 1.f / (e0 + e1 + e2 + e3);
    out[n*4+0] = e0 * is; out[n*4+1] = e1 * is; out[n*4+2] = e2 * is; out[n*4+3] = e3 * is;
  }
}

extern "C" void kernel_launch(void* const* d_in, const int* in_sizes, int n_in,
                              void* d_out, int out_size, void* d_ws, size_t ws_size,
                              hipStream_t stream){
  const float* x   = (const float*)d_in[0];
  const int*   ei  = (const int*)d_in[1];
  const float* ea  = (const float*)d_in[2];
  const float* Wp  = (const float*)d_in[3];
  const float* bp  = (const float*)d_in[4];
  const float* W1  = (const float*)d_in[5];
  const float* as1 = (const float*)d_in[6];
  const float* ad1 = (const float*)d_in[7];
  const float* We1 = (const float*)d_in[8];
  const float* ae1 = (const float*)d_in[9];
  const float* b1  = (const float*)d_in[10];
  const float* W2  = (const float*)d_in[11];
  const float* as2 = (const float*)d_in[12];
  const float* ad2 = (const float*)d_in[13];
  const float* We2 = (const float*)d_in[14];
  const float* ae2 = (const float*)d_in[15];
  const float* b2  = (const float*)d_in[16];
  const float* W3  = (const float*)d_in[17];
  const float* as3 = (const float*)d_in[18];
  const float* ad3 = (const float*)d_in[19];
  const float* We3 = (const float*)d_in[20];
  const float* ae3 = (const float*)d_in[21];
  const float* b3  = (const float*)d_in[22];
  const float* Wc  = (const float*)d_in[23];
  const float* bc  = (const float*)d_in[24];
  const int* srcI = ei;
  const int* dstI = ei + NE;

  char* base = (char*)d_ws;
  size_t off = 0;
  auto alloc = [&](size_t bytes) -> void* {
    void* p = base + off;
    off += (bytes + 255) & ~(size_t)255;
    return p;
  };
  float*  bufA  = (float*)alloc((size_t)NN * 256 * 4);
  __half* hB    = (__half*)alloc((size_t)NN * 256 * 2);
  __half* Wt1   = (__half*)alloc((size_t)64 * 256 * 2);
  __half* Wt2   = (__half*)alloc((size_t)256 * 256 * 2);
  __half* Wt3   = (__half*)alloc((size_t)256 * 64 * 2);
  int*   deg   = (int*)  alloc((size_t)NN * 4);
  int*   cnt   = (int*)  alloc((size_t)NN * 4);
  int*   rowptr= (int*)  alloc((size_t)(NN + 1) * 4);
  int*   bsum  = (int*)  alloc((size_t)NB_SC * 4);
  Edge*  edges = (Edge*) alloc((size_t)NE * sizeof(Edge));
  float* easum = (float*)alloc((size_t)NN * 3 * 4);
  float* aS    = (float*)alloc((size_t)NN * 4 * 4);
  float* aD    = (float*)alloc((size_t)NN * 4 * 4);
  float* g     = (float*)alloc(256);
  float* pbs   = (float*)alloc((size_t)NGB * 256 * 4);   // 4 MB block-major partials
  float* pbq   = (float*)alloc((size_t)NGB * 256 * 4);
  float* bmu   = (float*)alloc(256 * 4);
  float* brs   = (float*)alloc(256 * 4);
  (void)ws_size; (void)in_sizes; (void)n_in; (void)out_size;

  // CSR build + weight conversion
  hipMemsetAsync(deg, 0, (size_t)NN * 4, stream);
  hipMemsetAsync(cnt, 0, (size_t)NN * 4, stream);
  k_deg<<<(NE + 255) / 256, 256, 0, stream>>>(dstI, deg);
  k_scan1<<<NB_SC, 256, 0, stream>>>(deg, bsum);
  k_scan2<<<1, 256, 0, stream>>>(bsum, rowptr);
  k_scan3<<<NB_SC, 256, 0, stream>>>(deg, bsum, rowptr);
  k_fill<<<(NE + 255) / 256, 256, 0, stream>>>(srcI, dstI, ea, rowptr, cnt, edges);
  k_easum<<<(NN + 3) / 4, 256, 0, stream>>>(rowptr, edges, easum);
  k_wt3<<<(256 * 256 + 255) / 256, 256, 0, stream>>>(W1, W2, W3, Wt1, Wt2, Wt3);

  // input projection + BN stats (64-ch path)
  k_proj<<<(NN * 64 + 255) / 256, 256, 0, stream>>>(x, Wp, bp, bufA);
  k_bn_stats<64><<<512, 64, 0, stream>>>(bufA, pbs, pbq);
  k_bn_fin<64><<<1, 64, 0, stream>>>(pbs, pbq, bmu, brs);

  // ---- GAT layer 1 (64 -> 4x64); BN stats fused into k_gatn ----
  k_edge_g<4><<<1, 256, 0, stream>>>(We1, ae1, g);
  k_gemm_mfma<64, 256><<<(NN + 63) / 64, 256, 0, stream>>>(bufA, Wt1, bmu, brs, as1, ad1, hB, aS, aD);
  k_gatn<true><<<NGB, 256, 0, stream>>>(rowptr, edges, deg, easum, aS, aD, g, hB, b1, bufA, pbs, pbq);
  k_bn_finP<<<256, 256, 0, stream>>>(pbs, pbq, bmu, brs);

  // ---- GAT layer 2 (256 -> 4x64) ----
  k_edge_g<4><<<1, 256, 0, stream>>>(We2, ae2, g);
  k_gemm_mfma<256, 256><<<(NN + 63) / 64, 256, 0, stream>>>(bufA, Wt2, bmu, brs, as2, ad2, hB, aS, aD);
  k_gatn<true><<<NGB, 256, 0, stream>>>(rowptr, edges, deg, easum, aS, aD, g, hB, b2, bufA, pbs, pbq);
  k_bn_finP<<<256, 256, 0, stream>>>(pbs, pbq, bmu, brs);

  // ---- GAT layer 3 (256 -> 1x64), ELU fused ----
  k_edge_g<1><<<1, 64, 0, stream>>>(We3, ae3, g);
  k_gemm_mfma<256, 64><<<(NN + 63) / 64, 256, 0, stream>>>(bufA, Wt3, bmu, brs, as3, ad3, hB, aS, aD);
  k_gatw<1, true><<<(NN + 3) / 4, 256, 0, stream>>>(rowptr, edges, deg, easum, aS, aD, g, hB, b3, bufA);

  // ---- classifier + softmax ----
  k_final<<<NN, 64, 0, stream>>>(bufA, Wc, bc, (float*)d_out);
}

// Round 20
// 473.625 us; speedup vs baseline: 1.1407x; 1.0242x over previous
//
#include <hip/hip_runtime.h>
#include <hip/hip_fp16.h>
#include <math.h>

#define NN 50000
#define NE 800000
#define NEG 0.2f
#define EPS_BN 1e-5f
#define NROW 16384  // k_gatn grid rows (4096 blocks x 4 waves)
#define NGB  (NROW / 4)   // 4096 k_gatn blocks
#define NB_SC ((NN + 255) / 256)   // 196 scan blocks

typedef _Float16 f16x8 __attribute__((ext_vector_type(8)));
typedef float f32x4 __attribute__((ext_vector_type(4)));
struct H4 { __half2 a, b; };

struct __align__(16) Edge { int s; float e0, e1, e2; };

__device__ __forceinline__ float lrelu(float x){ return x > 0.f ? x : NEG * x; }
__device__ __forceinline__ float elu(float x){ return x > 0.f ? x : expm1f(x); }

// ---------------- CSR build ----------------
__global__ __launch_bounds__(256) void k_deg(const int* __restrict__ dst, int* __restrict__ deg){
  int e = blockIdx.x * 256 + threadIdx.x;
  if (e >= NE) return;
  atomicAdd(&deg[dst[e]], 1);
}

// 3-phase scan
__global__ __launch_bounds__(256) void k_scan1(const int* __restrict__ deg, int* __restrict__ bsum){
  __shared__ int sd[4];
  int t = threadIdx.x;
  int i = blockIdx.x * 256 + t;
  int v = (i < NN) ? deg[i] : 0;
  int s = v;
#pragma unroll
  for (int off = 32; off; off >>= 1) s += __shfl_down(s, off, 64);
  if ((t & 63) == 0) sd[t >> 6] = s;
  __syncthreads();
  if (t == 0) bsum[blockIdx.x] = sd[0] + sd[1] + sd[2] + sd[3];
}

__global__ __launch_bounds__(256) void k_scan2(int* __restrict__ bsum, int* __restrict__ rowptr){
  __shared__ int sm[256];
  int t = threadIdx.x;
  int v = (t < NB_SC) ? bsum[t] : 0;
  sm[t] = v;
  __syncthreads();
  for (int off = 1; off < 256; off <<= 1){
    int p = (t >= off) ? sm[t - off] : 0;
    __syncthreads();
    sm[t] += p;
    __syncthreads();
  }
  if (t < NB_SC) bsum[t] = sm[t] - v;
  if (t == 0) rowptr[NN] = NE;
}

__global__ __launch_bounds__(256) void k_scan3(const int* __restrict__ deg, const int* __restrict__ bsum,
                                               int* __restrict__ rowptr){
  __shared__ int sm[256];
  int t = threadIdx.x;
  int i = blockIdx.x * 256 + t;
  int v = (i < NN) ? deg[i] : 0;
  sm[t] = v;
  __syncthreads();
  for (int off = 1; off < 256; off <<= 1){
    int p = (t >= off) ? sm[t - off] : 0;
    __syncthreads();
    sm[t] += p;
    __syncthreads();
  }
  if (i < NN) rowptr[i] = bsum[blockIdx.x] + sm[t] - v;
}

__global__ __launch_bounds__(256) void k_fill(const int* __restrict__ src, const int* __restrict__ dst,
                                              const float* __restrict__ ea, const int* __restrict__ rowptr,
                                              int* __restrict__ cnt, Edge* __restrict__ edges){
  int e = blockIdx.x * 256 + threadIdx.x;
  if (e >= NE) return;
  int d = dst[e];
  int pos = rowptr[d] + atomicAdd(&cnt[d], 1);
  Edge ed;
  ed.s = src[e];
  ed.e0 = ea[e*3+0]; ed.e1 = ea[e*3+1]; ed.e2 = ea[e*3+2];
  edges[pos] = ed;
}

// easum[n] = sum of edge attrs over node n's CSR segment (1 wave/node)
__global__ __launch_bounds__(256) void k_easum(const int* __restrict__ rowptr, const Edge* __restrict__ edges,
                                               float* __restrict__ easum){
  int n = blockIdx.x * 4 + (threadIdx.x >> 6);
  int c = threadIdx.x & 63;
  if (n >= NN) return;
  int start = rowptr[n], end = rowptr[n + 1];
  float s0 = 0.f, s1 = 0.f, s2 = 0.f;
  for (int p = start + c; p < end; p += 64){
    Edge e = edges[p];
    s0 += e.e0; s1 += e.e1; s2 += e.e2;
  }
#pragma unroll
  for (int off = 32; off; off >>= 1){
    s0 += __shfl_down(s0, off, 64);
    s1 += __shfl_down(s1, off, 64);
    s2 += __shfl_down(s2, off, 64);
  }
  if (c == 0){ easum[n*3+0] = s0; easum[n*3+1] = s1; easum[n*3+2] = s2; }
}

// ---------------- input projection ----------------
__global__ __launch_bounds__(256) void k_proj(const float* __restrict__ x, const float* __restrict__ Wp,
                                              const float* __restrict__ bp, float* __restrict__ h0){
  int i = blockIdx.x * 256 + threadIdx.x;
  if (i >= NN * 64) return;
  int n = i >> 6, c = i & 63;
  h0[i] = fmaf(x[n*2+0], Wp[c], fmaf(x[n*2+1], Wp[64+c], bp[c]));
}

// ---------------- BatchNorm stats (64-ch path for layer 1 input) ----------------
template<int F>
__global__ void k_bn_stats(const float* __restrict__ x, float* __restrict__ ps, float* __restrict__ pq){
  int t = threadIdx.x;  // blockDim == F
  float s = 0.f, s2 = 0.f;
  for (int n = blockIdx.x; n < NN; n += 512){
    float v = x[(long)n * F + t];
    s += v; s2 += v * v;
  }
  ps[blockIdx.x * F + t] = s;
  pq[blockIdx.x * F + t] = s2;
}

template<int F>
__global__ void k_bn_fin(const float* __restrict__ ps, const float* __restrict__ pq,
                         float* __restrict__ mu, float* __restrict__ rs){
  int t = threadIdx.x;  // blockDim == F
  float s = 0.f, s2 = 0.f;
  for (int b = 0; b < 512; b++){ s += ps[b * F + t]; s2 += pq[b * F + t]; }
  float m = s * (1.f / NN);
  float var = s2 * (1.f / NN) - m * m;
  mu[t] = m;
  rs[t] = rsqrtf(var + EPS_BN);
}

// ---------------- 256-ch BN finalize from k_gatn's BLOCK-MAJOR partials ----------------
__global__ __launch_bounds__(256) void k_bn_finP(const float* __restrict__ pbs, const float* __restrict__ pbq,
                                                 float* __restrict__ mu, float* __restrict__ rs){
  __shared__ float sd[2][4];
  int c = blockIdx.x;
  int t = threadIdx.x;
  float s = 0.f, q = 0.f;
  for (int i = t; i < NGB; i += 256){ s += pbs[(long)i * 256 + c]; q += pbq[(long)i * 256 + c]; }
#pragma unroll
  for (int off = 32; off; off >>= 1){ s += __shfl_down(s, off, 64); q += __shfl_down(q, off, 64); }
  if ((t & 63) == 0){ sd[0][t >> 6] = s; sd[1][t >> 6] = q; }
  __syncthreads();
  if (t == 0){
    s = sd[0][0] + sd[0][1] + sd[0][2] + sd[0][3];
    q = sd[1][0] + sd[1][1] + sd[1][2] + sd[1][3];
    float m = s * (1.f / NN);
    float var = q * (1.f / NN) - m * m;
    mu[c] = m;
    rs[c] = rsqrtf(var + EPS_BN);
  }
}

// ---------------- all three weight transposes in one launch ----------------
__global__ __launch_bounds__(256) void k_wt3(const float* __restrict__ W1, const float* __restrict__ W2,
                                             const float* __restrict__ W3, __half* __restrict__ Wt1,
                                             __half* __restrict__ Wt2, __half* __restrict__ Wt3){
  int t = blockIdx.x * 256 + threadIdx.x;
  if (t < 64 * 256){
    int k = t / 256, j = t % 256;
    Wt1[(long)j * 64 + k] = __float2half(W1[t]);
  }
  if (t < 256 * 256){
    int k = t / 256, j = t % 256;
    Wt2[(long)j * 256 + k] = __float2half(W2[t]);
  }
  if (t < 256 * 64){
    int k = t / 64, j = t % 64;
    Wt3[(long)j * 256 + k] = __float2half(W3[t]);
  }
}

// ---------------- g[d][h] = sum_c We[d, h*64+c] * ae[h,c] ----------------
template<int H>
__global__ void k_edge_g(const float* __restrict__ We, const float* __restrict__ ae, float* __restrict__ g){
  int t = threadIdx.x;              // blockDim = H*64
  int h = t >> 6, c = t & 63;
  float a = ae[t];
  for (int d = 0; d < 3; d++){
    float p = We[d * (H*64) + t] * a;
    for (int off = 32; off; off >>= 1) p += __shfl_down(p, off, 64);
    if (c == 0) g[d * H + h] = p;
  }
  (void)h;
}

// ---------------- MFMA GEMM with fused BN+ELU on A (fp32 or fp16) + attn-coeff epilogue ----------------
template<int K, int J, bool AHALF>
__global__ __launch_bounds__(256) void k_gemm_mfma(const void* __restrict__ Avoid, const __half* __restrict__ Wt,
                                                   const float* __restrict__ mu, const float* __restrict__ rs,
                                                   const float* __restrict__ asrc, const float* __restrict__ adst,
                                                   __half* __restrict__ C, float* __restrict__ aS,
                                                   float* __restrict__ aD){
  constexpr int NS = J / 16;
  constexpr int KT = K / 32;
  constexpr int HH = J / 64;
  __shared__ __half Bs[J][40];
  int t = threadIdx.x;
  int w = t >> 6;
  int l = t & 63;
  int row0 = blockIdx.x * 64;
  int lr = l & 15;
  int lg = l >> 4;

  f32x4 acc[NS];
#pragma unroll
  for (int s = 0; s < NS; s++) acc[s] = (f32x4){0.f, 0.f, 0.f, 0.f};

  int arow = row0 + w * 16 + lr;
  bool aval = arow < NN;

  auto loadA = [&](int kt) -> f16x8 {
    f16x8 r;
#pragma unroll
    for (int k = 0; k < 8; k++) r[k] = (_Float16)0.f;
    if (aval){
      int k0 = kt * 32 + lg * 8;
      float v[8];
      if (AHALF){
        const __half* Arow = ((const __half*)Avoid) + (long)arow * K;
        f16x8 raw = *(const f16x8*)&Arow[k0];
#pragma unroll
        for (int k = 0; k < 8; k++) v[k] = (float)raw[k];
      } else {
        const float* Arow = ((const float*)Avoid) + (long)arow * K;
        float4 q0 = *(const float4*)&Arow[k0];
        float4 q1 = *(const float4*)&Arow[k0 + 4];
        v[0] = q0.x; v[1] = q0.y; v[2] = q0.z; v[3] = q0.w;
        v[4] = q1.x; v[5] = q1.y; v[6] = q1.z; v[7] = q1.w;
      }
      float4 m0 = *(const float4*)&mu[k0];
      float4 m1 = *(const float4*)&mu[k0 + 4];
      float4 r0 = *(const float4*)&rs[k0];
      float4 r1 = *(const float4*)&rs[k0 + 4];
      float mm[8] = {m0.x, m0.y, m0.z, m0.w, m1.x, m1.y, m1.z, m1.w};
      float rr[8] = {r0.x, r0.y, r0.z, r0.w, r1.x, r1.y, r1.z, r1.w};
#pragma unroll
      for (int k = 0; k < 8; k++) r[k] = (_Float16)elu((v[k] - mm[k]) * rr[k]);
    }
    return r;
  };

  f16x8 af_cur = loadA(0);

  for (int kt = 0; kt < KT; kt++){
    int kk = kt * 32;
#pragma unroll
    for (int i = 0; i < J / 64; i++){
      int ch = t + 256 * i;
      int c = ch >> 2, q = ch & 3;
      *(uint4*)&Bs[c][q * 8] = *(const uint4*)(Wt + (long)c * K + kk + q * 8);
    }
    __syncthreads();
    f16x8 af_nxt;
#pragma unroll
    for (int k = 0; k < 8; k++) af_nxt[k] = (_Float16)0.f;
    if (kt + 1 < KT) af_nxt = loadA(kt + 1);
#pragma unroll
    for (int s = 0; s < NS; s++){
      f16x8 bf = *(const f16x8*)&Bs[s * 16 + lr][lg * 8];
      acc[s] = __builtin_amdgcn_mfma_f32_16x16x32_f16(af_cur, bf, acc[s], 0, 0, 0);
    }
    __syncthreads();
    af_cur = af_nxt;
  }

  int orow = row0 + w * 16 + lg * 4;
  float sA[HH][4], dA[HH][4];
#pragma unroll
  for (int hd = 0; hd < HH; hd++)
#pragma unroll
    for (int i = 0; i < 4; i++){ sA[hd][i] = 0.f; dA[hd][i] = 0.f; }

#pragma unroll
  for (int s = 0; s < NS; s++){
    int cidx = s * 16 + lr;
    int hd = s >> 2;
    float a1 = asrc[cidx], a2 = adst[cidx];
#pragma unroll
    for (int i = 0; i < 4; i++){
      float v = acc[s][i];
      sA[hd][i] = fmaf(v, a1, sA[hd][i]);
      dA[hd][i] = fmaf(v, a2, dA[hd][i]);
      int r = orow + i;
      if (r < NN) C[(long)r * J + cidx] = __float2half(v);
    }
  }
#pragma unroll
  for (int off = 1; off <= 8; off <<= 1){
#pragma unroll
    for (int hd = 0; hd < HH; hd++)
#pragma unroll
      for (int i = 0; i < 4; i++){
        sA[hd][i] += __shfl_xor(sA[hd][i], off, 64);
        dA[hd][i] += __shfl_xor(dA[hd][i], off, 64);
      }
  }
  if (lr == 0){
#pragma unroll
    for (int i = 0; i < 4; i++){
      int r = orow + i;
      if (r < NN){
#pragma unroll
        for (int hd = 0; hd < HH; hd++){
          aS[r * HH + hd] = sA[hd][i];
          aD[r * HH + hd] = dA[hd][i];
        }
      }
    }
  }
}

// ---------------- H=4 fused GAT: ONE WAVE PER NODE + fused BN stats, fp16 out ----------------
// Agg loop has WAVE-UNIFORM trip count; __shfl executes unconditionally with a
// clamped slot index (CDNA ds_bpermute returns 0 from inactive source lanes).
// Stats accumulated in fp32 BEFORE fp16 rounding of out; partials combined
// across waves in LDS, written block-major (coalesced 1KB/block).
template<bool STATS>
__global__ __launch_bounds__(256) void k_gatn(const int* __restrict__ rowptr, const Edge* __restrict__ edges,
                                              const int* __restrict__ deg, const float* __restrict__ easum,
                                              const float* __restrict__ aS, const float* __restrict__ aD,
                                              const float* __restrict__ g4, const __half* __restrict__ hh,
                                              const float* __restrict__ bias, __half* __restrict__ out,
                                              float* __restrict__ pbs, float* __restrict__ pbq){
  const int W = 256;
  int wid = threadIdx.x >> 6;
  int lane = threadIdx.x & 63;
  int row = blockIdx.x * 4 + wid;      // 0..NROW-1
  int e4 = lane >> 2, hl = lane & 3;   // logit mapping
  int es = lane >> 5, ch8 = lane & 31; // agg mapping
  int c = ch8 * 8;                     // channel base 0..248
  int h2 = ch8 >> 3;                   // head of this channel group
  float g0 = g4[0*4+hl], g1 = g4[1*4+hl], g2 = g4[2*4+hl];
  float sum8[8], sq8[8];
  if (STATS){
#pragma unroll
    for (int k = 0; k < 8; k++){ sum8[k] = 0.f; sq8[k] = 0.f; }
  }

  for (int n = row; n < NN; n += NROW){
    int start = rowptr[n], end = rowptr[n+1];
    float adn = aD[n*4+hl];
    // self-loop (fill_value='mean')
    float dg = (float)deg[n];
    float inv = 1.f / fmaxf(dg, 1.f);
    float ll = aS[n*4+hl] + adn + g0*(easum[n*3+0]*inv) + g1*(easum[n*3+1]*inv) + g2*(easum[n*3+2]*inv);
    ll = lrelu(ll);
    float evl = __expf(ll);
    float evl2 = __shfl(evl, h2, 64);            // lane h2 holds head h2's evl
    f16x8 sv = *(const f16x8*)(hh + (long)n * W + c);
    float acc[8];
#pragma unroll
    for (int k = 0; k < 8; k++) acc[k] = (es == 0) ? evl2 * (float)sv[k] : 0.f;
    float denp = (lane < 4) ? evl : 0.f;

    for (int b0 = start; b0 < end; b0 += 16){
      int len = end - b0; if (len > 16) len = 16;
      float ev = 0.f; unsigned pk = 0;
      if (e4 < len){
        Edge e = edges[b0 + e4];
        float l = lrelu(aS[e.s*4+hl] + adn + g0*e.e0 + g1*e.e1 + g2*e.e2);
        ev = __expf(l);
        pk = ((unsigned)e.s << 16) | (unsigned)__half_as_ushort(__float2half(ev));
      }
      denp += ev;
      int iters = (len + 1) >> 1;                // uniform trip count
      for (int i = 0; i < iters; i++){
        int j = i * 2 + es;                      // may equal len (odd len, es=1)
        bool valid = j < len;
        int jj = valid ? j : 0;
        unsigned pj = __shfl((int)pk, jj * 4 + h2, 64);  // full-wave shuffle: sources active
        float aj = valid ? __half2float(__ushort_as_half((unsigned short)(pj & 0xffffu))) : 0.f;
        int sj = (int)(pj >> 16);
        f16x8 v = *(const f16x8*)(hh + (long)sj * W + c);
#pragma unroll
        for (int k = 0; k < 8; k++) acc[k] = fmaf(aj, (float)v[k], acc[k]);
      }
    }
    // den reduce over e4 (fold bits 2..5), leaves per-head den on lanes by hl
#pragma unroll
    for (int off = 4; off <= 32; off <<= 1) denp += __shfl_xor(denp, off, 64);
    float den2 = __shfl(denp, h2, 64);
    // combine the two edge slots
#pragma unroll
    for (int k = 0; k < 8; k++) acc[k] += __shfl_xor(acc[k], 32, 64);
    if (es == 0){
      float invd = 1.f / (den2 + 1e-16f);
      float4 b0v = *(const float4*)&bias[c];
      float4 b1v = *(const float4*)&bias[c+4];
      acc[0] = fmaf(acc[0], invd, b0v.x); acc[1] = fmaf(acc[1], invd, b0v.y);
      acc[2] = fmaf(acc[2], invd, b0v.z); acc[3] = fmaf(acc[3], invd, b0v.w);
      acc[4] = fmaf(acc[4], invd, b1v.x); acc[5] = fmaf(acc[5], invd, b1v.y);
      acc[6] = fmaf(acc[6], invd, b1v.z); acc[7] = fmaf(acc[7], invd, b1v.w);
      if (STATS){
#pragma unroll
        for (int k = 0; k < 8; k++){ sum8[k] += acc[k]; sq8[k] += acc[k]*acc[k]; }
      }
      H4 o;
      o.a = __floats2half2_rn(acc[0], acc[1]);
      o.b = __floats2half2_rn(acc[2], acc[3]);
      *(H4*)&out[(long)n * W + c] = o;
      o.a = __floats2half2_rn(acc[4], acc[5]);
      o.b = __floats2half2_rn(acc[6], acc[7]);
      *(H4*)&out[(long)n * W + c + 4] = o;
    }
  }

  if (STATS){
    __shared__ float ls[4][256];
    __shared__ float lq[4][256];
    if (es == 0){
#pragma unroll
      for (int k = 0; k < 8; k++){ ls[wid][c + k] = sum8[k]; lq[wid][c + k] = sq8[k]; }
    }
    __syncthreads();
    int ch = threadIdx.x;   // 256 threads = 256 channels
    float s = ls[0][ch] + ls[1][ch] + ls[2][ch] + ls[3][ch];
    float q = lq[0][ch] + lq[1][ch] + lq[2][ch] + lq[3][ch];
    pbs[(long)blockIdx.x * 256 + ch] = s;   // block-major: coalesced 1KB per block
    pbq[(long)blockIdx.x * 256 + ch] = q;
  }
}

// ---------------- H=1 fused per-wave GAT (layer 3) ----------------
template<int H, bool ELU>
__global__ __launch_bounds__(256) void k_gatw(const int* __restrict__ rowptr, const Edge* __restrict__ edges,
                                              const int* __restrict__ deg, const float* __restrict__ easum,
                                              const float* __restrict__ aS, const float* __restrict__ aD,
                                              const float* __restrict__ g, const __half* __restrict__ hh,
                                              const float* __restrict__ bias, float* __restrict__ out){
  constexpr int W = H * 64;
  int wid = threadIdx.x >> 6;
  int lane = threadIdx.x & 63;
  int n = blockIdx.x * 4 + wid;
  int h = 0;
  if (n >= NN) return;
  int start = rowptr[n], end = rowptr[n + 1];
  float g0 = g[0*H+h], g1 = g[1*H+h], g2 = g[2*H+h];
  float adn = aD[n*H+h];
  int ch8 = lane >> 3;
  int es = lane & 7;

  float dg = (float)deg[n];
  float inv = 1.f / fmaxf(dg, 1.f);
  float ll = aS[n*H+h] + adn + g0*(easum[n*3+0]*inv) + g1*(easum[n*3+1]*inv) + g2*(easum[n*3+2]*inv);
  ll = lrelu(ll);
  float evl = __expf(ll);
  f16x8 sv = *(const f16x8*)(hh + (long)n * W + h * 64 + ch8 * 8);
  float acc[8];
#pragma unroll
  for (int k = 0; k < 8; k++) acc[k] = (es == 0) ? evl * (float)sv[k] : 0.f;
  float denp = (lane == 0) ? evl : 0.f;

  for (int base0 = start; base0 < end; base0 += 64){
    int len = end - base0; if (len > 64) len = 64;
    float ev = 0.f;
    unsigned pk = 0;
    if (lane < len){
      Edge e = edges[base0 + lane];
      float l = lrelu(aS[e.s*H+h] + adn + g0*e.e0 + g1*e.e1 + g2*e.e2);
      ev = __expf(l);
      pk = ((unsigned)e.s << 16) | (unsigned)__half_as_ushort(__float2half(ev));
    }
    denp += ev;
    for (int j = es; j < len; j += 8){
      unsigned pj = __shfl((int)pk, j, 64);
      float aj = __half2float(__ushort_as_half((unsigned short)(pj & 0xffffu)));
      int sj = (int)(pj >> 16);
      f16x8 v = *(const f16x8*)(hh + (long)sj * W + h * 64 + ch8 * 8);
#pragma unroll
      for (int k = 0; k < 8; k++) acc[k] = fmaf(aj, (float)v[k], acc[k]);
    }
  }

#pragma unroll
  for (int off = 32; off; off >>= 1) denp += __shfl_xor(denp, off, 64);
#pragma unroll
  for (int k = 0; k < 8; k++){
    acc[k] += __shfl_xor(acc[k], 1, 64);
    acc[k] += __shfl_xor(acc[k], 2, 64);
    acc[k] += __shfl_xor(acc[k], 4, 64);
  }
  if (es == 0){
    float invden = 1.f / (denp + 1e-16f);
    int cb = h * 64 + ch8 * 8;
    float4 b0 = *(const float4*)&bias[cb];
    float4 b1 = *(const float4*)&bias[cb + 4];
    float bb[8] = {b0.x, b0.y, b0.z, b0.w, b1.x, b1.y, b1.z, b1.w};
#pragma unroll
    for (int k = 0; k < 8; k++){
      acc[k] = acc[k] * invden + bb[k];
      if (ELU) acc[k] = acc[k] > 0.f ? acc[k] : expm1f(acc[k]);
    }
    float4 o0 = make_float4(acc[0], acc[1], acc[2], acc[3]);
    float4 o1 = make_float4(acc[4], acc[5], acc[6], acc[7]);
    *(float4*)&out[(long)n * W + cb] = o0;
    *(float4*)&out[(long)n * W + cb + 4] = o1;
  }
}

// ---------------- final linear 64->4 + softmax ----------------
__global__ __launch_bounds__(64) void k_final(const float* __restrict__ h3, const float* __restrict__ Wc,
                                              const float* __restrict__ bc, float* __restrict__ out){
  int n = blockIdx.x;
  int c = threadIdx.x;  // 64
  float v = h3[(long)n * 64 + c];
  float r0 = v * Wc[c*4+0], r1 = v * Wc[c*4+1], r2 = v * Wc[c*4+2], r3 = v * Wc[c*4+3];
  for (int off = 32; off; off >>= 1){
    r0 += __shfl_down(r0, off, 64);
    r1 += __shfl_down(r1, off, 64);
    r2 += __shfl_down(r2, off, 64);
    r3 += __shfl_down(r3, off, 64);
  }
  if (c == 0){
    r0 += bc[0]; r1 += bc[1]; r2 += bc[2]; r3 += bc[3];
    float mm = fmaxf(fmaxf(r0, r1), fmaxf(r2, r3));
    float e0 = __expf(r0 - mm), e1 = __expf(r1 - mm), e2 = __expf(r2 - mm), e3 = __expf(r3 - mm);
    float is = 1.f / (e0 + e1 + e2 + e3);
    out[n*4+0] = e0 * is; out[n*4+1] = e1 * is; out[n*4+2] = e2 * is; out[n*4+3] = e3 * is;
  }
}

extern "C" void kernel_launch(void* const* d_in, const int* in_sizes, int n_in,
                              void* d_out, int out_size, void* d_ws, size_t ws_size,
                              hipStream_t stream){
  const float* x   = (const float*)d_in[0];
  const int*   ei  = (const int*)d_in[1];
  const float* ea  = (const float*)d_in[2];
  const float* Wp  = (const float*)d_in[3];
  const float* bp  = (const float*)d_in[4];
  const float* W1  = (const float*)d_in[5];
  const float* as1 = (const float*)d_in[6];
  const float* ad1 = (const float*)d_in[7];
  const float* We1 = (const float*)d_in[8];
  const float* ae1 = (const float*)d_in[9];
  const float* b1  = (const float*)d_in[10];
  const float* W2  = (const float*)d_in[11];
  const float* as2 = (const float*)d_in[12];
  const float* ad2 = (const float*)d_in[13];
  const float* We2 = (const float*)d_in[14];
  const float* ae2 = (const float*)d_in[15];
  const float* b2  = (const float*)d_in[16];
  const float* W3  = (const float*)d_in[17];
  const float* as3 = (const float*)d_in[18];
  const float* ad3 = (const float*)d_in[19];
  const float* We3 = (const float*)d_in[20];
  const float* ae3 = (const float*)d_in[21];
  const float* b3  = (const float*)d_in[22];
  const float* Wc  = (const float*)d_in[23];
  const float* bc  = (const float*)d_in[24];
  const int* srcI = ei;
  const int* dstI = ei + NE;

  char* base = (char*)d_ws;
  size_t off = 0;
  auto alloc = [&](size_t bytes) -> void* {
    void* p = base + off;
    off += (bytes + 255) & ~(size_t)255;
    return p;
  };
  float*  bufA  = (float*)alloc((size_t)NN * 64 * 4);    // proj out / gatw out / final in
  __half* hA    = (__half*)alloc((size_t)NN * 256 * 2);  // k_gatn out -> GEMM A
  __half* hB    = (__half*)alloc((size_t)NN * 256 * 2);  // GEMM out -> gather payload
  __half* Wt1   = (__half*)alloc((size_t)64 * 256 * 2);
  __half* Wt2   = (__half*)alloc((size_t)256 * 256 * 2);
  __half* Wt3   = (__half*)alloc((size_t)256 * 64 * 2);
  int*   deg   = (int*)  alloc((size_t)NN * 4);
  int*   cnt   = (int*)  alloc((size_t)NN * 4);
  int*   rowptr= (int*)  alloc((size_t)(NN + 1) * 4);
  int*   bsum  = (int*)  alloc((size_t)NB_SC * 4);
  Edge*  edges = (Edge*) alloc((size_t)NE * sizeof(Edge));
  float* easum = (float*)alloc((size_t)NN * 3 * 4);
  float* aS    = (float*)alloc((size_t)NN * 4 * 4);
  float* aD    = (float*)alloc((size_t)NN * 4 * 4);
  float* g     = (float*)alloc(256);
  float* pbs   = (float*)alloc((size_t)NGB * 256 * 4);   // 4 MB block-major partials
  float* pbq   = (float*)alloc((size_t)NGB * 256 * 4);
  float* bmu   = (float*)alloc(256 * 4);
  float* brs   = (float*)alloc(256 * 4);
  (void)ws_size; (void)in_sizes; (void)n_in; (void)out_size;

  // CSR build + weight conversion
  hipMemsetAsync(deg, 0, (size_t)NN * 4, stream);
  hipMemsetAsync(cnt, 0, (size_t)NN * 4, stream);
  k_deg<<<(NE + 255) / 256, 256, 0, stream>>>(dstI, deg);
  k_scan1<<<NB_SC, 256, 0, stream>>>(deg, bsum);
  k_scan2<<<1, 256, 0, stream>>>(bsum, rowptr);
  k_scan3<<<NB_SC, 256, 0, stream>>>(deg, bsum, rowptr);
  k_fill<<<(NE + 255) / 256, 256, 0, stream>>>(srcI, dstI, ea, rowptr, cnt, edges);
  k_easum<<<(NN + 3) / 4, 256, 0, stream>>>(rowptr, edges, easum);
  k_wt3<<<(256 * 256 + 255) / 256, 256, 0, stream>>>(W1, W2, W3, Wt1, Wt2, Wt3);

  // input projection + BN stats (64-ch path)
  k_proj<<<(NN * 64 + 255) / 256, 256, 0, stream>>>(x, Wp, bp, bufA);
  k_bn_stats<64><<<512, 64, 0, stream>>>(bufA, pbs, pbq);
  k_bn_fin<64><<<1, 64, 0, stream>>>(pbs, pbq, bmu, brs);

  // ---- GAT layer 1 (64 -> 4x64); BN stats fused into k_gatn ----
  k_edge_g<4><<<1, 256, 0, stream>>>(We1, ae1, g);
  k_gemm_mfma<64, 256, false><<<(NN + 63) / 64, 256, 0, stream>>>(bufA, Wt1, bmu, brs, as1, ad1, hB, aS, aD);
  k_gatn<true><<<NGB, 256, 0, stream>>>(rowptr, edges, deg, easum, aS, aD, g, hB, b1, hA, pbs, pbq);
  k_bn_finP<<<256, 256, 0, stream>>>(pbs, pbq, bmu, brs);

  // ---- GAT layer 2 (256 -> 4x64) ----
  k_edge_g<4><<<1, 256, 0, stream>>>(We2, ae2, g);
  k_gemm_mfma<256, 256, true><<<(NN + 63) / 64, 256, 0, stream>>>(hA, Wt2, bmu, brs, as2, ad2, hB, aS, aD);
  k_gatn<true><<<NGB, 256, 0, stream>>>(rowptr, edges, deg, easum, aS, aD, g, hB, b2, hA, pbs, pbq);
  k_bn_finP<<<256, 256, 0, stream>>>(pbs, pbq, bmu, brs);

  // ---- GAT layer 3 (256 -> 1x64), ELU fused ----
  k_edge_g<1><<<1, 64, 0, stream>>>(We3, ae3, g);
  k_gemm_mfma<256, 64, true><<<(NN + 63) / 64, 256, 0, stream>>>(hA, Wt3, bmu, brs, as3, ad3, hB, aS, aD);
  k_gatw<1, true><<<(NN + 3) / 4, 256, 0, stream>>>(rowptr, edges, deg, easum, aS, aD, g, hB, b3, bufA);

  // ---- classifier + softmax ----
  k_final<<<NN, 64, 0, stream>>>(bufA, Wc, bc, (float*)d_out);
}

// Round 21
// 443.006 us; speedup vs baseline: 1.2195x; 1.0691x over previous
//
#include <hip/hip_runtime.h>
#include <hip/hip_fp16.h>
#include <math.h>

#define NN 50000
#define NE 800000
#define NEG 0.2f
#define EPS_BN 1e-5f
#define NROW 16384  // k_gatn grid rows (4096 blocks x 4 waves)
#define NGB  (NROW / 4)   // 4096 k_gatn blocks
#define NB_SC ((NN + 255) / 256)   // 196 scan blocks
#define PAD256(x) (((size_t)(x) + 255) & ~(size_t)255)

typedef _Float16 f16x8 __attribute__((ext_vector_type(8)));
typedef float f32x4 __attribute__((ext_vector_type(4)));
struct H4 { __half2 a, b; };

struct __align__(16) Edge { int s; float e0, e1, e2; };

__device__ __forceinline__ float lrelu(float x){ return x > 0.f ? x : NEG * x; }
__device__ __forceinline__ float elu(float x){ return x > 0.f ? x : expm1f(x); }

// ---------------- CSR build ----------------
__global__ __launch_bounds__(256) void k_deg(const int* __restrict__ dst, int* __restrict__ deg){
  int e = blockIdx.x * 256 + threadIdx.x;
  if (e >= NE) return;
  atomicAdd(&deg[dst[e]], 1);
}

// 3-phase scan
__global__ __launch_bounds__(256) void k_scan1(const int* __restrict__ deg, int* __restrict__ bsum){
  __shared__ int sd[4];
  int t = threadIdx.x;
  int i = blockIdx.x * 256 + t;
  int v = (i < NN) ? deg[i] : 0;
  int s = v;
#pragma unroll
  for (int off = 32; off; off >>= 1) s += __shfl_down(s, off, 64);
  if ((t & 63) == 0) sd[t >> 6] = s;
  __syncthreads();
  if (t == 0) bsum[blockIdx.x] = sd[0] + sd[1] + sd[2] + sd[3];
}

__global__ __launch_bounds__(256) void k_scan2(int* __restrict__ bsum, int* __restrict__ rowptr){
  __shared__ int sm[256];
  int t = threadIdx.x;
  int v = (t < NB_SC) ? bsum[t] : 0;
  sm[t] = v;
  __syncthreads();
  for (int off = 1; off < 256; off <<= 1){
    int p = (t >= off) ? sm[t - off] : 0;
    __syncthreads();
    sm[t] += p;
    __syncthreads();
  }
  if (t < NB_SC) bsum[t] = sm[t] - v;
  if (t == 0) rowptr[NN] = NE;
}

__global__ __launch_bounds__(256) void k_scan3(const int* __restrict__ deg, const int* __restrict__ bsum,
                                               int* __restrict__ rowptr){
  __shared__ int sm[256];
  int t = threadIdx.x;
  int i = blockIdx.x * 256 + t;
  int v = (i < NN) ? deg[i] : 0;
  sm[t] = v;
  __syncthreads();
  for (int off = 1; off < 256; off <<= 1){
    int p = (t >= off) ? sm[t - off] : 0;
    __syncthreads();
    sm[t] += p;
    __syncthreads();
  }
  if (i < NN) rowptr[i] = bsum[blockIdx.x] + sm[t] - v;
}

__global__ __launch_bounds__(256) void k_fill(const int* __restrict__ src, const int* __restrict__ dst,
                                              const float* __restrict__ ea, const int* __restrict__ rowptr,
                                              int* __restrict__ cnt, Edge* __restrict__ edges){
  int e = blockIdx.x * 256 + threadIdx.x;
  if (e >= NE) return;
  int d = dst[e];
  int pos = rowptr[d] + atomicAdd(&cnt[d], 1);
  Edge ed;
  ed.s = src[e];
  ed.e0 = ea[e*3+0]; ed.e1 = ea[e*3+1]; ed.e2 = ea[e*3+2];
  edges[pos] = ed;
}

// easum[n] = sum of edge attrs over node n's CSR segment (1 wave/node)
__global__ __launch_bounds__(256) void k_easum(const int* __restrict__ rowptr, const Edge* __restrict__ edges,
                                               float* __restrict__ easum){
  int n = blockIdx.x * 4 + (threadIdx.x >> 6);
  int c = threadIdx.x & 63;
  if (n >= NN) return;
  int start = rowptr[n], end = rowptr[n + 1];
  float s0 = 0.f, s1 = 0.f, s2 = 0.f;
  for (int p = start + c; p < end; p += 64){
    Edge e = edges[p];
    s0 += e.e0; s1 += e.e1; s2 += e.e2;
  }
#pragma unroll
  for (int off = 32; off; off >>= 1){
    s0 += __shfl_down(s0, off, 64);
    s1 += __shfl_down(s1, off, 64);
    s2 += __shfl_down(s2, off, 64);
  }
  if (c == 0){ easum[n*3+0] = s0; easum[n*3+1] = s1; easum[n*3+2] = s2; }
}

// ---------------- input projection + fused BN stats ----------------
// 512 blocks x 256 threads; thread = (sub, ch); per-block 64-ch partials.
__global__ __launch_bounds__(256) void k_proj_stats(const float* __restrict__ x, const float* __restrict__ Wp,
                                                    const float* __restrict__ bp, float* __restrict__ h0,
                                                    float* __restrict__ ps, float* __restrict__ pq){
  __shared__ float ls[4][64], lq[4][64];
  int t = threadIdx.x;
  int ch = t & 63, sub = t >> 6;
  float wc0 = Wp[ch], wc1 = Wp[64 + ch], bc0 = bp[ch];
  float s = 0.f, s2 = 0.f;
  for (int n = blockIdx.x * 4 + sub; n < NN; n += 512 * 4){
    float v = fmaf(x[n*2+0], wc0, fmaf(x[n*2+1], wc1, bc0));
    h0[(long)n * 64 + ch] = v;
    s += v; s2 += v * v;
  }
  ls[sub][ch] = s; lq[sub][ch] = s2;
  __syncthreads();
  if (t < 64){
    ps[blockIdx.x * 64 + t] = ls[0][t] + ls[1][t] + ls[2][t] + ls[3][t];
    pq[blockIdx.x * 64 + t] = lq[0][t] + lq[1][t] + lq[2][t] + lq[3][t];
  }
}

template<int F>
__global__ void k_bn_fin(const float* __restrict__ ps, const float* __restrict__ pq,
                         float* __restrict__ mu, float* __restrict__ rs){
  int t = threadIdx.x;  // blockDim == F
  float s = 0.f, s2 = 0.f;
  for (int b = 0; b < 512; b++){ s += ps[b * F + t]; s2 += pq[b * F + t]; }
  float m = s * (1.f / NN);
  float var = s2 * (1.f / NN) - m * m;
  mu[t] = m;
  rs[t] = rsqrtf(var + EPS_BN);
}

// ---------------- 256-ch BN finalize from k_gatn's BLOCK-MAJOR partials ----------------
__global__ __launch_bounds__(256) void k_bn_finP(const float* __restrict__ pbs, const float* __restrict__ pbq,
                                                 float* __restrict__ mu, float* __restrict__ rs){
  __shared__ float sd[2][4];
  int c = blockIdx.x;
  int t = threadIdx.x;
  float s = 0.f, q = 0.f;
  for (int i = t; i < NGB; i += 256){ s += pbs[(long)i * 256 + c]; q += pbq[(long)i * 256 + c]; }
#pragma unroll
  for (int off = 32; off; off >>= 1){ s += __shfl_down(s, off, 64); q += __shfl_down(q, off, 64); }
  if ((t & 63) == 0){ sd[0][t >> 6] = s; sd[1][t >> 6] = q; }
  __syncthreads();
  if (t == 0){
    s = sd[0][0] + sd[0][1] + sd[0][2] + sd[0][3];
    q = sd[1][0] + sd[1][1] + sd[1][2] + sd[1][3];
    float m = s * (1.f / NN);
    float var = q * (1.f / NN) - m * m;
    mu[c] = m;
    rs[c] = rsqrtf(var + EPS_BN);
  }
}

// ---------------- all three weight transposes in one launch ----------------
__global__ __launch_bounds__(256) void k_wt3(const float* __restrict__ W1, const float* __restrict__ W2,
                                             const float* __restrict__ W3, __half* __restrict__ Wt1,
                                             __half* __restrict__ Wt2, __half* __restrict__ Wt3){
  int t = blockIdx.x * 256 + threadIdx.x;
  if (t < 64 * 256){
    int k = t / 256, j = t % 256;
    Wt1[(long)j * 64 + k] = __float2half(W1[t]);
  }
  if (t < 256 * 256){
    int k = t / 256, j = t % 256;
    Wt2[(long)j * 256 + k] = __float2half(W2[t]);
  }
  if (t < 256 * 64){
    int k = t / 64, j = t % 64;
    Wt3[(long)j * 256 + k] = __float2half(W3[t]);
  }
}

// ---------------- g[d][h] = sum_c We[d, h*64+c] * ae[h,c] ----------------
template<int H>
__global__ void k_edge_g(const float* __restrict__ We, const float* __restrict__ ae, float* __restrict__ g){
  int t = threadIdx.x;              // blockDim = H*64
  int h = t >> 6, c = t & 63;
  float a = ae[t];
  for (int d = 0; d < 3; d++){
    float p = We[d * (H*64) + t] * a;
    for (int off = 32; off; off >>= 1) p += __shfl_down(p, off, 64);
    if (c == 0) g[d * H + h] = p;
  }
  (void)h;
}

// ---------------- MFMA GEMM with fused BN+ELU on A (fp32 or fp16) + attn-coeff epilogue ----------------
template<int K, int J, bool AHALF>
__global__ __launch_bounds__(256) void k_gemm_mfma(const void* __restrict__ Avoid, const __half* __restrict__ Wt,
                                                   const float* __restrict__ mu, const float* __restrict__ rs,
                                                   const float* __restrict__ asrc, const float* __restrict__ adst,
                                                   __half* __restrict__ C, float* __restrict__ aS,
                                                   float* __restrict__ aD){
  constexpr int NS = J / 16;
  constexpr int KT = K / 32;
  constexpr int HH = J / 64;
  __shared__ __half Bs[J][40];
  int t = threadIdx.x;
  int w = t >> 6;
  int l = t & 63;
  int row0 = blockIdx.x * 64;
  int lr = l & 15;
  int lg = l >> 4;

  f32x4 acc[NS];
#pragma unroll
  for (int s = 0; s < NS; s++) acc[s] = (f32x4){0.f, 0.f, 0.f, 0.f};

  int arow = row0 + w * 16 + lr;
  bool aval = arow < NN;

  auto loadA = [&](int kt) -> f16x8 {
    f16x8 r;
#pragma unroll
    for (int k = 0; k < 8; k++) r[k] = (_Float16)0.f;
    if (aval){
      int k0 = kt * 32 + lg * 8;
      float v[8];
      if (AHALF){
        const __half* Arow = ((const __half*)Avoid) + (long)arow * K;
        f16x8 raw = *(const f16x8*)&Arow[k0];
#pragma unroll
        for (int k = 0; k < 8; k++) v[k] = (float)raw[k];
      } else {
        const float* Arow = ((const float*)Avoid) + (long)arow * K;
        float4 q0 = *(const float4*)&Arow[k0];
        float4 q1 = *(const float4*)&Arow[k0 + 4];
        v[0] = q0.x; v[1] = q0.y; v[2] = q0.z; v[3] = q0.w;
        v[4] = q1.x; v[5] = q1.y; v[6] = q1.z; v[7] = q1.w;
      }
      float4 m0 = *(const float4*)&mu[k0];
      float4 m1 = *(const float4*)&mu[k0 + 4];
      float4 r0 = *(const float4*)&rs[k0];
      float4 r1 = *(const float4*)&rs[k0 + 4];
      float mm[8] = {m0.x, m0.y, m0.z, m0.w, m1.x, m1.y, m1.z, m1.w};
      float rr[8] = {r0.x, r0.y, r0.z, r0.w, r1.x, r1.y, r1.z, r1.w};
#pragma unroll
      for (int k = 0; k < 8; k++) r[k] = (_Float16)elu((v[k] - mm[k]) * rr[k]);
    }
    return r;
  };

  f16x8 af_cur = loadA(0);

  for (int kt = 0; kt < KT; kt++){
    int kk = kt * 32;
#pragma unroll
    for (int i = 0; i < J / 64; i++){
      int ch = t + 256 * i;
      int c = ch >> 2, q = ch & 3;
      *(uint4*)&Bs[c][q * 8] = *(const uint4*)(Wt + (long)c * K + kk + q * 8);
    }
    __syncthreads();
    f16x8 af_nxt;
#pragma unroll
    for (int k = 0; k < 8; k++) af_nxt[k] = (_Float16)0.f;
    if (kt + 1 < KT) af_nxt = loadA(kt + 1);
#pragma unroll
    for (int s = 0; s < NS; s++){
      f16x8 bf = *(const f16x8*)&Bs[s * 16 + lr][lg * 8];
      acc[s] = __builtin_amdgcn_mfma_f32_16x16x32_f16(af_cur, bf, acc[s], 0, 0, 0);
    }
    __syncthreads();
    af_cur = af_nxt;
  }

  int orow = row0 + w * 16 + lg * 4;
  float sA[HH][4], dA[HH][4];
#pragma unroll
  for (int hd = 0; hd < HH; hd++)
#pragma unroll
    for (int i = 0; i < 4; i++){ sA[hd][i] = 0.f; dA[hd][i] = 0.f; }

#pragma unroll
  for (int s = 0; s < NS; s++){
    int cidx = s * 16 + lr;
    int hd = s >> 2;
    float a1 = asrc[cidx], a2 = adst[cidx];
#pragma unroll
    for (int i = 0; i < 4; i++){
      float v = acc[s][i];
      sA[hd][i] = fmaf(v, a1, sA[hd][i]);
      dA[hd][i] = fmaf(v, a2, dA[hd][i]);
      int r = orow + i;
      if (r < NN) C[(long)r * J + cidx] = __float2half(v);
    }
  }
#pragma unroll
  for (int off = 1; off <= 8; off <<= 1){
#pragma unroll
    for (int hd = 0; hd < HH; hd++)
#pragma unroll
      for (int i = 0; i < 4; i++){
        sA[hd][i] += __shfl_xor(sA[hd][i], off, 64);
        dA[hd][i] += __shfl_xor(dA[hd][i], off, 64);
      }
  }
  if (lr == 0){
#pragma unroll
    for (int i = 0; i < 4; i++){
      int r = orow + i;
      if (r < NN){
#pragma unroll
        for (int hd = 0; hd < HH; hd++){
          aS[r * HH + hd] = sA[hd][i];
          aD[r * HH + hd] = dA[hd][i];
        }
      }
    }
  }
}

// ---------------- H=4 fused GAT: ONE WAVE PER NODE + fused BN stats, fp16 out ----------------
template<bool STATS>
__global__ __launch_bounds__(256) void k_gatn(const int* __restrict__ rowptr, const Edge* __restrict__ edges,
                                              const int* __restrict__ deg, const float* __restrict__ easum,
                                              const float* __restrict__ aS, const float* __restrict__ aD,
                                              const float* __restrict__ g4, const __half* __restrict__ hh,
                                              const float* __restrict__ bias, __half* __restrict__ out,
                                              float* __restrict__ pbs, float* __restrict__ pbq){
  const int W = 256;
  int wid = threadIdx.x >> 6;
  int lane = threadIdx.x & 63;
  int row = blockIdx.x * 4 + wid;      // 0..NROW-1
  int e4 = lane >> 2, hl = lane & 3;   // logit mapping
  int es = lane >> 5, ch8 = lane & 31; // agg mapping
  int c = ch8 * 8;                     // channel base 0..248
  int h2 = ch8 >> 3;                   // head of this channel group
  float g0 = g4[0*4+hl], g1 = g4[1*4+hl], g2 = g4[2*4+hl];
  float sum8[8], sq8[8];
  if (STATS){
#pragma unroll
    for (int k = 0; k < 8; k++){ sum8[k] = 0.f; sq8[k] = 0.f; }
  }

  for (int n = row; n < NN; n += NROW){
    int start = rowptr[n], end = rowptr[n+1];
    float adn = aD[n*4+hl];
    // self-loop (fill_value='mean')
    float dg = (float)deg[n];
    float inv = 1.f / fmaxf(dg, 1.f);
    float ll = aS[n*4+hl] + adn + g0*(easum[n*3+0]*inv) + g1*(easum[n*3+1]*inv) + g2*(easum[n*3+2]*inv);
    ll = lrelu(ll);
    float evl = __expf(ll);
    float evl2 = __shfl(evl, h2, 64);            // lane h2 holds head h2's evl
    f16x8 sv = *(const f16x8*)(hh + (long)n * W + c);
    float acc[8];
#pragma unroll
    for (int k = 0; k < 8; k++) acc[k] = (es == 0) ? evl2 * (float)sv[k] : 0.f;
    float denp = (lane < 4) ? evl : 0.f;

    for (int b0 = start; b0 < end; b0 += 16){
      int len = end - b0; if (len > 16) len = 16;
      float ev = 0.f; unsigned pk = 0;
      if (e4 < len){
        Edge e = edges[b0 + e4];
        float l = lrelu(aS[e.s*4+hl] + adn + g0*e.e0 + g1*e.e1 + g2*e.e2);
        ev = __expf(l);
        pk = ((unsigned)e.s << 16) | (unsigned)__half_as_ushort(__float2half(ev));
      }
      denp += ev;
      int iters = (len + 1) >> 1;                // uniform trip count
      for (int i = 0; i < iters; i++){
        int j = i * 2 + es;                      // may equal len (odd len, es=1)
        bool valid = j < len;
        int jj = valid ? j : 0;
        unsigned pj = __shfl((int)pk, jj * 4 + h2, 64);  // full-wave shuffle: sources active
        float aj = valid ? __half2float(__ushort_as_half((unsigned short)(pj & 0xffffu))) : 0.f;
        int sj = (int)(pj >> 16);
        f16x8 v = *(const f16x8*)(hh + (long)sj * W + c);
#pragma unroll
        for (int k = 0; k < 8; k++) acc[k] = fmaf(aj, (float)v[k], acc[k]);
      }
    }
    // den reduce over e4 (fold bits 2..5), leaves per-head den on lanes by hl
#pragma unroll
    for (int off = 4; off <= 32; off <<= 1) denp += __shfl_xor(denp, off, 64);
    float den2 = __shfl(denp, h2, 64);
    // combine the two edge slots
#pragma unroll
    for (int k = 0; k < 8; k++) acc[k] += __shfl_xor(acc[k], 32, 64);
    if (es == 0){
      float invd = 1.f / (den2 + 1e-16f);
      float4 b0v = *(const float4*)&bias[c];
      float4 b1v = *(const float4*)&bias[c+4];
      acc[0] = fmaf(acc[0], invd, b0v.x); acc[1] = fmaf(acc[1], invd, b0v.y);
      acc[2] = fmaf(acc[2], invd, b0v.z); acc[3] = fmaf(acc[3], invd, b0v.w);
      acc[4] = fmaf(acc[4], invd, b1v.x); acc[5] = fmaf(acc[5], invd, b1v.y);
      acc[6] = fmaf(acc[6], invd, b1v.z); acc[7] = fmaf(acc[7], invd, b1v.w);
      if (STATS){
#pragma unroll
        for (int k = 0; k < 8; k++){ sum8[k] += acc[k]; sq8[k] += acc[k]*acc[k]; }
      }
      H4 o;
      o.a = __floats2half2_rn(acc[0], acc[1]);
      o.b = __floats2half2_rn(acc[2], acc[3]);
      *(H4*)&out[(long)n * W + c] = o;
      o.a = __floats2half2_rn(acc[4], acc[5]);
      o.b = __floats2half2_rn(acc[6], acc[7]);
      *(H4*)&out[(long)n * W + c + 4] = o;
    }
  }

  if (STATS){
    __shared__ float ls[4][256];
    __shared__ float lq[4][256];
    if (es == 0){
#pragma unroll
      for (int k = 0; k < 8; k++){ ls[wid][c + k] = sum8[k]; lq[wid][c + k] = sq8[k]; }
    }
    __syncthreads();
    int ch = threadIdx.x;   // 256 threads = 256 channels
    float s = ls[0][ch] + ls[1][ch] + ls[2][ch] + ls[3][ch];
    float q = lq[0][ch] + lq[1][ch] + lq[2][ch] + lq[3][ch];
    pbs[(long)blockIdx.x * 256 + ch] = s;   // block-major: coalesced 1KB per block
    pbq[(long)blockIdx.x * 256 + ch] = q;
  }
}

// ---------------- H=1 GAT layer 3 + fused 64->4 classifier + softmax ----------------
// After slot-combine, ALL lanes normalize+bias+ELU their 8 channels (garbage on
// es!=0 lanes is harmless), compute 8x4 partial dot with Wc, reduce across the
// es==0 lane class via shfl_xor(8/16/32) (lane congruence mod 8 keeps the tree
// inside the class; full-wave shuffles keep sources active). Lane 0: softmax.
__global__ __launch_bounds__(256) void k_gatw_final(const int* __restrict__ rowptr, const Edge* __restrict__ edges,
                                                    const int* __restrict__ deg, const float* __restrict__ easum,
                                                    const float* __restrict__ aS, const float* __restrict__ aD,
                                                    const float* __restrict__ g, const __half* __restrict__ hh,
                                                    const float* __restrict__ bias, const float* __restrict__ Wc,
                                                    const float* __restrict__ bc, float* __restrict__ out4){
  const int W = 64;
  int wid = threadIdx.x >> 6;
  int lane = threadIdx.x & 63;
  int n = blockIdx.x * 4 + wid;
  if (n >= NN) return;
  int start = rowptr[n], end = rowptr[n + 1];
  float g0 = g[0], g1 = g[1], g2 = g[2];
  float adn = aD[n];
  int ch8 = lane >> 3;
  int es = lane & 7;

  float dg = (float)deg[n];
  float inv = 1.f / fmaxf(dg, 1.f);
  float ll = aS[n] + adn + g0*(easum[n*3+0]*inv) + g1*(easum[n*3+1]*inv) + g2*(easum[n*3+2]*inv);
  ll = lrelu(ll);
  float evl = __expf(ll);
  f16x8 sv = *(const f16x8*)(hh + (long)n * W + ch8 * 8);
  float acc[8];
#pragma unroll
  for (int k = 0; k < 8; k++) acc[k] = (es == 0) ? evl * (float)sv[k] : 0.f;
  float denp = (lane == 0) ? evl : 0.f;

  for (int base0 = start; base0 < end; base0 += 64){
    int len = end - base0; if (len > 64) len = 64;
    float ev = 0.f;
    unsigned pk = 0;
    if (lane < len){
      Edge e = edges[base0 + lane];
      float l = lrelu(aS[e.s] + adn + g0*e.e0 + g1*e.e1 + g2*e.e2);
      ev = __expf(l);
      pk = ((unsigned)e.s << 16) | (unsigned)__half_as_ushort(__float2half(ev));
    }
    denp += ev;
    for (int j = es; j < len; j += 8){
      unsigned pj = __shfl((int)pk, j, 64);
      float aj = __half2float(__ushort_as_half((unsigned short)(pj & 0xffffu)));
      int sj = (int)(pj >> 16);
      f16x8 v = *(const f16x8*)(hh + (long)sj * W + ch8 * 8);
#pragma unroll
      for (int k = 0; k < 8; k++) acc[k] = fmaf(aj, (float)v[k], acc[k]);
    }
  }

#pragma unroll
  for (int off = 32; off; off >>= 1) denp += __shfl_xor(denp, off, 64);
#pragma unroll
  for (int k = 0; k < 8; k++){
    acc[k] += __shfl_xor(acc[k], 1, 64);
    acc[k] += __shfl_xor(acc[k], 2, 64);
    acc[k] += __shfl_xor(acc[k], 4, 64);
  }
  // normalize + bias + ELU on all lanes (only es==0 lanes hold valid acc)
  float invden = 1.f / (denp + 1e-16f);
  int cb = ch8 * 8;
  float4 b0 = *(const float4*)&bias[cb];
  float4 b1 = *(const float4*)&bias[cb + 4];
  float bb[8] = {b0.x, b0.y, b0.z, b0.w, b1.x, b1.y, b1.z, b1.w};
#pragma unroll
  for (int k = 0; k < 8; k++){
    acc[k] = acc[k] * invden + bb[k];
    acc[k] = acc[k] > 0.f ? acc[k] : expm1f(acc[k]);
  }
  // classifier partial dot: r[j] = sum_k acc[k] * Wc[(cb+k)*4 + j]
  float r[4] = {0.f, 0.f, 0.f, 0.f};
#pragma unroll
  for (int k = 0; k < 8; k++){
    float4 wrow = *(const float4*)&Wc[(cb + k) * 4];
    r[0] = fmaf(acc[k], wrow.x, r[0]);
    r[1] = fmaf(acc[k], wrow.y, r[1]);
    r[2] = fmaf(acc[k], wrow.z, r[2]);
    r[3] = fmaf(acc[k], wrow.w, r[3]);
  }
#pragma unroll
  for (int k = 0; k < 4; k++){
    r[k] += __shfl_xor(r[k], 8, 64);
    r[k] += __shfl_xor(r[k], 16, 64);
    r[k] += __shfl_xor(r[k], 32, 64);
  }
  if (lane == 0){
    float r0 = r[0] + bc[0], r1 = r[1] + bc[1], r2 = r[2] + bc[2], r3 = r[3] + bc[3];
    float mm = fmaxf(fmaxf(r0, r1), fmaxf(r2, r3));
    float e0 = __expf(r0 - mm), e1 = __expf(r1 - mm), e2 = __expf(r2 - mm), e3 = __expf(r3 - mm);
    float is = 1.f / (e0 + e1 + e2 + e3);
    *(float4*)&out4[n*4] = make_float4(e0 * is, e1 * is, e2 * is, e3 * is);
  }
}

extern "C" void kernel_launch(void* const* d_in, const int* in_sizes, int n_in,
                              void* d_out, int out_size, void* d_ws, size_t ws_size,
                              hipStream_t stream){
  const float* x   = (const float*)d_in[0];
  const int*   ei  = (const int*)d_in[1];
  const float* ea  = (const float*)d_in[2];
  const float* Wp  = (const float*)d_in[3];
  const float* bp  = (const float*)d_in[4];
  const float* W1  = (const float*)d_in[5];
  const float* as1 = (const float*)d_in[6];
  const float* ad1 = (const float*)d_in[7];
  const float* We1 = (const float*)d_in[8];
  const float* ae1 = (const float*)d_in[9];
  const float* b1  = (const float*)d_in[10];
  const float* W2  = (const float*)d_in[11];
  const float* as2 = (const float*)d_in[12];
  const float* ad2 = (const float*)d_in[13];
  const float* We2 = (const float*)d_in[14];
  const float* ae2 = (const float*)d_in[15];
  const float* b2  = (const float*)d_in[16];
  const float* W3  = (const float*)d_in[17];
  const float* as3 = (const float*)d_in[18];
  const float* ad3 = (const float*)d_in[19];
  const float* We3 = (const float*)d_in[20];
  const float* ae3 = (const float*)d_in[21];
  const float* b3  = (const float*)d_in[22];
  const float* Wc  = (const float*)d_in[23];
  const float* bc  = (const float*)d_in[24];
  const int* srcI = ei;
  const int* dstI = ei + NE;

  char* base = (char*)d_ws;
  size_t off = 0;
  auto alloc = [&](size_t bytes) -> void* {
    void* p = base + off;
    off += PAD256(bytes);
    return p;
  };
  float*  bufA  = (float*)alloc((size_t)NN * 64 * 4);    // proj out
  __half* hA    = (__half*)alloc((size_t)NN * 256 * 2);  // k_gatn out -> GEMM A
  __half* hB    = (__half*)alloc((size_t)NN * 256 * 2);  // GEMM out -> gather payload
  __half* Wt1   = (__half*)alloc((size_t)64 * 256 * 2);
  __half* Wt2   = (__half*)alloc((size_t)256 * 256 * 2);
  __half* Wt3   = (__half*)alloc((size_t)256 * 64 * 2);
  int*   deg   = (int*)  alloc((size_t)NN * 4);
  int*   cnt   = (int*)  alloc((size_t)NN * 4);
  int*   rowptr= (int*)  alloc((size_t)(NN + 1) * 4);
  int*   bsum  = (int*)  alloc((size_t)NB_SC * 4);
  Edge*  edges = (Edge*) alloc((size_t)NE * sizeof(Edge));
  float* easum = (float*)alloc((size_t)NN * 3 * 4);
  float* aS    = (float*)alloc((size_t)NN * 4 * 4);
  float* aD    = (float*)alloc((size_t)NN * 4 * 4);
  float* g     = (float*)alloc(256);
  float* pbs   = (float*)alloc((size_t)NGB * 256 * 4);   // 4 MB block-major partials
  float* pbq   = (float*)alloc((size_t)NGB * 256 * 4);
  float* bmu   = (float*)alloc(256 * 4);
  float* brs   = (float*)alloc(256 * 4);
  (void)ws_size; (void)in_sizes; (void)n_in; (void)out_size;

  // CSR build + weight conversion (deg & cnt are adjacent -> one memset)
  hipMemsetAsync(deg, 0, PAD256((size_t)NN * 4) + (size_t)NN * 4, stream);
  k_deg<<<(NE + 255) / 256, 256, 0, stream>>>(dstI, deg);
  k_scan1<<<NB_SC, 256, 0, stream>>>(deg, bsum);
  k_scan2<<<1, 256, 0, stream>>>(bsum, rowptr);
  k_scan3<<<NB_SC, 256, 0, stream>>>(deg, bsum, rowptr);
  k_fill<<<(NE + 255) / 256, 256, 0, stream>>>(srcI, dstI, ea, rowptr, cnt, edges);
  k_easum<<<(NN + 3) / 4, 256, 0, stream>>>(rowptr, edges, easum);
  k_wt3<<<(256 * 256 + 255) / 256, 256, 0, stream>>>(W1, W2, W3, Wt1, Wt2, Wt3);

  // input projection with fused BN stats (64-ch path)
  k_proj_stats<<<512, 256, 0, stream>>>(x, Wp, bp, bufA, pbs, pbq);
  k_bn_fin<64><<<1, 64, 0, stream>>>(pbs, pbq, bmu, brs);

  // ---- GAT layer 1 (64 -> 4x64); BN stats fused into k_gatn ----
  k_edge_g<4><<<1, 256, 0, stream>>>(We1, ae1, g);
  k_gemm_mfma<64, 256, false><<<(NN + 63) / 64, 256, 0, stream>>>(bufA, Wt1, bmu, brs, as1, ad1, hB, aS, aD);
  k_gatn<true><<<NGB, 256, 0, stream>>>(rowptr, edges, deg, easum, aS, aD, g, hB, b1, hA, pbs, pbq);
  k_bn_finP<<<256, 256, 0, stream>>>(pbs, pbq, bmu, brs);

  // ---- GAT layer 2 (256 -> 4x64) ----
  k_edge_g<4><<<1, 256, 0, stream>>>(We2, ae2, g);
  k_gemm_mfma<256, 256, true><<<(NN + 63) / 64, 256, 0, stream>>>(hA, Wt2, bmu, brs, as2, ad2, hB, aS, aD);
  k_gatn<true><<<NGB, 256, 0, stream>>>(rowptr, edges, deg, easum, aS, aD, g, hB, b2, hA, pbs, pbq);
  k_bn_finP<<<256, 256, 0, stream>>>(pbs, pbq, bmu, brs);

  // ---- GAT layer 3 (256 -> 1x64) + classifier + softmax, all fused ----
  k_edge_g<1><<<1, 64, 0, stream>>>(We3, ae3, g);
  k_gemm_mfma<256, 64, true><<<(NN + 63) / 64, 256, 0, stream>>>(hA, Wt3, bmu, brs, as3, ad3, hB, aS, aD);
  k_gatw_final<<<(NN + 3) / 4, 256, 0, stream>>>(rowptr, edges, deg, easum, aS, aD, g, hB, b3, Wc, bc, (float*)d_out);
}